// Round 1
// 765.067 us; speedup vs baseline: 1.1100x; 1.1100x over previous
//
#include <hip/hip_runtime.h>

// LocalAttention (Swin scrambled-window variant) — all four GEMMs on MFMA.
// Window map (verified pass R2/R3): n=b*1024+c*16+t ; c2=hi*32+lo ; p=r*8+s ;
// h=16t+8hi+r ; w=8lo+s ; mask index = n&1023.
// l2norm folds into k:  attn[i][j] = sum_c q[c][i] * (k[c][j]*0.125/(nq_c*nk_c)).
// Split-bf16 everywhere: x=hi+lo, D += Ah*Bh + Ah*Bl + Al*Bh (rel err ~2^-18).
//
// R4: fp32 planes/projo XOR-swizzle  p' = p ^ (((ch>>1)&7)<<2)  (16B granular).
//   Old layout: DWc stencil reads had bank-start = 16(cp&1)+8(rr&3) -> only 4
//   distinct 16B slots, 16 lanes each => ~16-way conflict, ~80% of the measured
//   8.0e7 SQ_LDS_BANK_CONFLICT. Swizzling by cp (not ch! chi is fixed per
//   instruction) spreads lanes uniformly over all 8 slots. Applied consistently
//   at: P2 store, DWc read, DWw write, TR read, P7 store, P8 read.
//
// Phases (one block = one window, 9 barriers):
//  P1 load+split -> XTin[p][c]      TR  transpose q,k -> qT/kT [pixel][c] bf16
//  P2 MFMA 1x1 qkv -> fp32 planes   VB  v regs -> vbf [c][p] bf16
//  DWc dw3x3 -> regs (+norms)       P5  MFMA QK^T + mask + softmax -> PT[j][i]
//  DWw q,k(scaled) -> planes        P6  MFMA V*A -> XT[p][c]
//                                   P7  MFMA proj (9 shifted GEMMs) -> projo
//                                   P8  window-reverse(+roll) store

typedef __attribute__((ext_vector_type(8))) short bf8;
typedef __attribute__((ext_vector_type(4))) float f32x4;
#define MFMA(a, b, c) __builtin_amdgcn_mfma_f32_16x16x32_bf16(a, b, c, 0, 0, 0)

// fp32 plane swizzle: channel ch, pixel p (0..63) -> dword index within region.
// XOR bits 2-4 of the pixel index with (ch>>1)&7; keeps p' in [0,64), keeps
// 16B alignment of 4-aligned p.
__device__ __forceinline__ int pswz(int ch, int p) {
    return ch * 72 + (p ^ (((ch >> 1) & 7) << 2));
}

__device__ __forceinline__ void bsplit(float f, short& h, short& l) {
    unsigned u = __float_as_uint(f);
    unsigned hb = (u + 0x7FFFu + ((u >> 16) & 1u)) >> 16;
    float hf = __uint_as_float(hb << 16);
    float r = f - hf;
    unsigned u2 = __float_as_uint(r);
    unsigned lb = (u2 + 0x7FFFu + ((u2 >> 16) & 1u)) >> 16;
    h = (short)hb; l = (short)lb;
}
__device__ __forceinline__ void bsplit2(float a, float b, unsigned& hw, unsigned& lw) {
    short ha, la, hb_, lb_;
    bsplit(a, ha, la); bsplit(b, hb_, lb_);
    hw = (unsigned)(unsigned short)ha | ((unsigned)(unsigned short)hb_ << 16);
    lw = (unsigned)(unsigned short)la | ((unsigned)(unsigned short)lb_ << 16);
}

// ---- qkv 1x1 weight fragments: [kk(2)][tt(12)][lane(64)][j(8)]  B[n=oc][k=ic] ----
__global__ void k_fq(const float* __restrict__ wq, short* __restrict__ oh, short* __restrict__ ol) {
    int bx = blockIdx.x;                 // kk*12 + tt
    int kk = bx / 12, tt = bx % 12;
    int tid = threadIdx.x;               // 512
    int lane = tid >> 3, j = tid & 7;
    int oc = tt * 16 + (lane & 15);
    int ic = kk * 32 + ((lane >> 4) << 3) + j;
    short h, l; bsplit(wq[oc * 64 + ic], h, l);
    oh[bx * 512 + tid] = h; ol[bx * 512 + tid] = l;
}
// ---- proj 3x3 weight fragments: [tap(9)][kk(2)][tt(4)][lane(64)][j(8)] ----
__global__ void k_fp(const float* __restrict__ wp, short* __restrict__ oh, short* __restrict__ ol) {
    int bx = blockIdx.x;                 // tap*8 + kk*4 + tt
    int tap = bx >> 3, kk = (bx >> 2) & 1, tt = bx & 3;
    int tid = threadIdx.x;
    int lane = tid >> 3, j = tid & 7;
    int oc = tt * 16 + (lane & 15);
    int ic = kk * 32 + ((lane >> 4) << 3) + j;
    short h, l; bsplit(wp[(oc * 64 + ic) * 9 + tap], h, l);
    oh[bx * 512 + tid] = h; ol[bx * 512 + tid] = l;
}

// dw3x3 for a channel pair, one output row (8 px), window-local zero pad.
// Reads the swizzled planes layout (pswz).
__device__ __forceinline__ void dw_pair(const float* planes, const float* wdw,
                                        int ch0, int row, float o[2][8]) {
    #pragma unroll
    for (int chi = 0; chi < 2; ++chi) {
        int ch = ch0 + chi;
        const float* pl = planes;
        const float* wd = wdw + ch * 9;
        float w9[9];
        #pragma unroll
        for (int tp = 0; tp < 9; ++tp) w9[tp] = wd[tp];
        float e[3][10];
        #pragma unroll
        for (int k3 = 0; k3 < 3; ++k3) {
            int rr = row - 1 + k3;
            e[k3][0] = 0.f; e[k3][9] = 0.f;
            if ((unsigned)rr < 8u) {
                float4 a = *(const float4*)&pl[pswz(ch, rr * 8)];
                float4 b = *(const float4*)&pl[pswz(ch, rr * 8 + 4)];
                e[k3][1] = a.x; e[k3][2] = a.y; e[k3][3] = a.z; e[k3][4] = a.w;
                e[k3][5] = b.x; e[k3][6] = b.y; e[k3][7] = b.z; e[k3][8] = b.w;
            } else {
                #pragma unroll
                for (int q2 = 1; q2 < 9; ++q2) e[k3][q2] = 0.f;
            }
        }
        #pragma unroll
        for (int s = 0; s < 8; ++s) {
            float a = 0.f;
            #pragma unroll
            for (int k3 = 0; k3 < 3; ++k3)
                #pragma unroll
                for (int dx = 0; dx < 3; ++dx)
                    a = fmaf(w9[k3 * 3 + dx], e[k3][s + dx], a);
            o[chi][s] = a;
        }
    }
}

__global__ __launch_bounds__(256, 2)
void k_fused(const float* __restrict__ in,
             const short* __restrict__ bqh, const short* __restrict__ bql,
             const float* __restrict__ wdw,
             const short* __restrict__ bph, const short* __restrict__ bpl,
             float* __restrict__ out, int shift, int use_mask, int roll)
{
    // Region plan (74016 B total, overlaid by live-range):
    //  [0,55296)   planes: 192x72 fp32 (P2 out, dw in/out, TR in) — SWIZZLED
    //    post-TR:  vbh/vbl [0,18432) ; PTh/PTl [18432,36864) ; kTh/kTl [36864,55296)
    //    post-P6:  projo (64x72 fp32, SWIZZLED) at [0,18432)
    //  [55296,74016) XT: 65x72 bf16 hi/lo — XTin -> qT -> attn-out(+zero row 64)
    __shared__ __align__(16) char smem[74016];
    float* planes = (float*)smem;
    short* vbh = (short*)smem;
    short* vbl = (short*)(smem + 9216);
    short* PTh = (short*)(smem + 18432);
    short* PTl = (short*)(smem + 27648);
    short* kTh = (short*)(smem + 36864);
    short* kTl = (short*)(smem + 46080);
    short* XTh = (short*)(smem + 55296);
    short* XTl = (short*)(smem + 55296 + 9360);
    float* projo = (float*)smem;

    const int tid = threadIdx.x, lane = tid & 63, wv = tid >> 6;
    const int col = lane & 15, quad = lane >> 4, qo8 = quad * 8;
    const int mh = wv & 1, nh = wv >> 1;
    const int n = blockIdx.x;
    const int b = n >> 10, c = (n >> 4) & 63, t = n & 15;
    const size_t base = ((size_t)(b * 64 + c)) << 16;

    // ---- P1: load window (shift folded), split, XTin[p][c2] ----
    #pragma unroll
    for (int k = 0; k < 16; ++k) {
        int o = tid + k * 256;
        int hi = o >> 11, r = (o >> 8) & 7, lo = (o >> 3) & 31, s = o & 7;
        int h2 = t * 16 + hi * 8 + r, w2 = lo * 8 + s;
        float v = in[base + (size_t)((h2 + shift) & 255) * 256 + ((w2 + shift) & 255)];
        short hh, ll; bsplit(v, hh, ll);
        int p = r * 8 + s, c2 = hi * 32 + lo;
        XTh[p * 72 + c2] = hh; XTl[p * 72 + c2] = ll;
    }
    __syncthreads();   // (1)

    // ---- P2: MFMA 1x1. M=p, N=oc(192), K=ic(64). wave: 2 m-tiles x 6 n-tiles ----
    {
        f32x4 acc[2][6];
        #pragma unroll
        for (int mt = 0; mt < 2; ++mt)
            #pragma unroll
            for (int nt = 0; nt < 6; ++nt) acc[mt][nt] = (f32x4){0.f, 0.f, 0.f, 0.f};
        #pragma unroll
        for (int kk = 0; kk < 2; ++kk) {
            bf8 Ah[2], Al[2];
            #pragma unroll
            for (int mt = 0; mt < 2; ++mt) {
                int ad = ((mh * 2 + mt) * 16 + col) * 72 + kk * 32 + qo8;
                Ah[mt] = *(const bf8*)&XTh[ad];
                Al[mt] = *(const bf8*)&XTl[ad];
            }
            #pragma unroll
            for (int nt = 0; nt < 6; ++nt) {
                int tt = nh * 6 + nt;
                bf8 Bh = *(const bf8*)&bqh[((kk * 12 + tt) * 64 + lane) * 8];
                bf8 Bl = *(const bf8*)&bql[((kk * 12 + tt) * 64 + lane) * 8];
                #pragma unroll
                for (int mt = 0; mt < 2; ++mt) {
                    acc[mt][nt] = MFMA(Ah[mt], Bh, acc[mt][nt]);
                    acc[mt][nt] = MFMA(Ah[mt], Bl, acc[mt][nt]);
                    acc[mt][nt] = MFMA(Al[mt], Bh, acc[mt][nt]);
                }
            }
        }
        #pragma unroll
        for (int nt = 0; nt < 6; ++nt) {
            int oc = (nh * 6 + nt) * 16 + col;
            #pragma unroll
            for (int mt = 0; mt < 2; ++mt) {
                int p0 = (mh * 2 + mt) * 16 + quad * 4;
                *(f32x4*)&planes[pswz(oc, p0)] = acc[mt][nt];   // swizzled, 2-way free
            }
        }
    }
    __syncthreads();   // (2)

    // ---- DWc: dw3x3 into regs; per-channel norms via 8-lane shfl; fold scale into k ----
    const int cp = tid >> 3, rrow = tid & 7;
    float dq[2][8], dk[2][8], dv[2][8];
    float nq[2];
    dw_pair(planes, wdw, 2 * cp, rrow, dq);
    #pragma unroll
    for (int chi = 0; chi < 2; ++chi) {
        float ss = 0.f;
        #pragma unroll
        for (int s = 0; s < 8; ++s) ss = fmaf(dq[chi][s], dq[chi][s], ss);
        ss += __shfl_xor(ss, 1); ss += __shfl_xor(ss, 2); ss += __shfl_xor(ss, 4);
        nq[chi] = fmaxf(sqrtf(ss), 1e-12f);
    }
    dw_pair(planes, wdw, 64 + 2 * cp, rrow, dk);
    #pragma unroll
    for (int chi = 0; chi < 2; ++chi) {
        float ss = 0.f;
        #pragma unroll
        for (int s = 0; s < 8; ++s) ss = fmaf(dk[chi][s], dk[chi][s], ss);
        ss += __shfl_xor(ss, 1); ss += __shfl_xor(ss, 2); ss += __shfl_xor(ss, 4);
        float nk = fmaxf(sqrtf(ss), 1e-12f);
        float sc = 0.125f / (nq[chi] * nk);
        #pragma unroll
        for (int s = 0; s < 8; ++s) dk[chi][s] *= sc;
    }
    dw_pair(planes, wdw, 128 + 2 * cp, rrow, dv);
    __syncthreads();   // (3a) all stencil reads complete

    // ---- DWw: q, k(scaled) back to planes (swizzled float4 rows); v stays in regs ----
    #pragma unroll
    for (int chi = 0; chi < 2; ++chi) {
        int chq = 2 * cp + chi;
        *(float4*)&planes[pswz(chq, rrow * 8)] =
            (float4){dq[chi][0], dq[chi][1], dq[chi][2], dq[chi][3]};
        *(float4*)&planes[pswz(chq, rrow * 8 + 4)] =
            (float4){dq[chi][4], dq[chi][5], dq[chi][6], dq[chi][7]};
        int chk = 64 + 2 * cp + chi;
        *(float4*)&planes[pswz(chk, rrow * 8)] =
            (float4){dk[chi][0], dk[chi][1], dk[chi][2], dk[chi][3]};
        *(float4*)&planes[pswz(chk, rrow * 8 + 4)] =
            (float4){dk[chi][4], dk[chi][5], dk[chi][6], dk[chi][7]};
    }
    __syncthreads();   // (3b)

    // ---- TR: transpose q,k planes -> qT(=XT region) / kT  [pixel][c] bf16 split ----
    #pragma unroll
    for (int it2 = 0; it2 < 8; ++it2) {
        int pq = wv * 4 + ((it2 + (lane >> 2)) & 3);   // rotation spreads bank windows
        int ch = lane + ((it2 >= 4) ? 64 : 0);
        const float* src = planes + pswz(ch, pq * 4);
        float4 vle = *(const float4*)src;
        short* dh = (it2 < 4) ? XTh : kTh;
        short* dl = (it2 < 4) ? XTl : kTl;
        float vv[4] = {vle.x, vle.y, vle.z, vle.w};
        #pragma unroll
        for (int j = 0; j < 4; ++j) {
            short hh, ll; bsplit(vv[j], hh, ll);
            dh[(pq * 4 + j) * 72 + lane] = hh;
            dl[(pq * 4 + j) * 72 + lane] = ll;
        }
    }
    // zero row 64 of XT region (pad row for P7's shifted reads)
    if (tid < 36) { ((unsigned*)&XTh[64 * 72])[tid] = 0u; ((unsigned*)&XTl[64 * 72])[tid] = 0u; }
    __syncthreads();   // (4)

    // ---- VB: v regs -> vbf [c][p] bf16 split (b128 rows, conflict-free) ----
    #pragma unroll
    for (int chi = 0; chi < 2; ++chi) {
        unsigned hw[4], lw[4];
        #pragma unroll
        for (int q2 = 0; q2 < 4; ++q2) bsplit2(dv[chi][2 * q2], dv[chi][2 * q2 + 1], hw[q2], lw[q2]);
        int ad = (2 * cp + chi) * 72 + rrow * 8;
        *(uint4*)&vbh[ad] = (uint4){hw[0], hw[1], hw[2], hw[3]};
        *(uint4*)&vbl[ad] = (uint4){lw[0], lw[1], lw[2], lw[3]};
    }

    // ---- P5: MFMA QK^T (M=i rows wv*16.., N=j all 64, K=c) + mask + softmax ----
    f32x4 at[4];
    #pragma unroll
    for (int nt = 0; nt < 4; ++nt) at[nt] = (f32x4){0.f, 0.f, 0.f, 0.f};
    {
        bf8 Ah[2], Al[2];
        #pragma unroll
        for (int kk = 0; kk < 2; ++kk) {
            int ad = (wv * 16 + col) * 72 + kk * 32 + qo8;
            Ah[kk] = *(const bf8*)&XTh[ad];   // qT
            Al[kk] = *(const bf8*)&XTl[ad];
        }
        #pragma unroll
        for (int kk = 0; kk < 2; ++kk)
            #pragma unroll
            for (int nt = 0; nt < 4; ++nt) {
                int ad = (nt * 16 + col) * 72 + kk * 32 + qo8;
                bf8 Bh = *(const bf8*)&kTh[ad];
                bf8 Bl = *(const bf8*)&kTl[ad];
                at[nt] = MFMA(Ah[kk], Bh, at[nt]);
                at[nt] = MFMA(Ah[kk], Bl, at[nt]);
                at[nt] = MFMA(Al[kk], Bh, at[nt]);
            }
    }
    if (use_mask) {
        const int widx = n & 1023;
        const int hn_m = widx >> 5, wn_m = widx & 31;
        #pragma unroll
        for (int nt = 0; nt < 4; ++nt) {
            int j = nt * 16 + col;
            int rj = ((hn_m == 31) ? (((j >> 3) < 4) ? 1 : 2) : 0) * 3
                   + ((wn_m == 31) ? (((j & 7) < 4) ? 1 : 2) : 0);
            #pragma unroll
            for (int rg = 0; rg < 4; ++rg) {
                int i = wv * 16 + quad * 4 + rg;
                int ri = ((hn_m == 31) ? (((i >> 3) < 4) ? 1 : 2) : 0) * 3
                       + ((wn_m == 31) ? (((i & 7) < 4) ? 1 : 2) : 0);
                if (ri != rj) at[nt][rg] = at[nt][rg] - 100.f;
            }
        }
    }
    float Pv[4][4];
    #pragma unroll
    for (int rg = 0; rg < 4; ++rg) {
        float m = fmaxf(fmaxf(at[0][rg], at[1][rg]), fmaxf(at[2][rg], at[3][rg]));
        m = fmaxf(m, __shfl_xor(m, 1)); m = fmaxf(m, __shfl_xor(m, 2));
        m = fmaxf(m, __shfl_xor(m, 4)); m = fmaxf(m, __shfl_xor(m, 8));
        float e0 = __expf(at[0][rg] - m), e1 = __expf(at[1][rg] - m);
        float e2 = __expf(at[2][rg] - m), e3 = __expf(at[3][rg] - m);
        float s = e0 + e1 + e2 + e3;
        s += __shfl_xor(s, 1); s += __shfl_xor(s, 2);
        s += __shfl_xor(s, 4); s += __shfl_xor(s, 8);
        float is = 1.0f / s;
        Pv[0][rg] = e0 * is; Pv[1][rg] = e1 * is; Pv[2][rg] = e2 * is; Pv[3][rg] = e3 * is;
    }
    __syncthreads();   // (5) all qT/kT reads done

    // ---- PT write: PT[j][i] bf16 split (2-way, free) ----
    #pragma unroll
    for (int nt = 0; nt < 4; ++nt) {
        int j = nt * 16 + col;
        #pragma unroll
        for (int rp = 0; rp < 2; ++rp) {
            unsigned hw, lw; bsplit2(Pv[nt][2 * rp], Pv[nt][2 * rp + 1], hw, lw);
            int ad = j * 72 + wv * 16 + quad * 4 + 2 * rp;
            *(unsigned*)&PTh[ad] = hw; *(unsigned*)&PTl[ad] = lw;
        }
    }
    __syncthreads();   // (6)

    // ---- P6: MFMA V*A. M=c, N=j, K=i. A=vbf[c][i], B=PT[j][i]. D -> XT[p=j][c] ----
    {
        f32x4 av[2][2];
        #pragma unroll
        for (int mt = 0; mt < 2; ++mt)
            #pragma unroll
            for (int nt = 0; nt < 2; ++nt) av[mt][nt] = (f32x4){0.f, 0.f, 0.f, 0.f};
        #pragma unroll
        for (int kk = 0; kk < 2; ++kk) {
            bf8 Ah[2], Al[2], Bh[2], Bl[2];
            #pragma unroll
            for (int mt = 0; mt < 2; ++mt) {
                int ad = ((mh * 2 + mt) * 16 + col) * 72 + kk * 32 + qo8;
                Ah[mt] = *(const bf8*)&vbh[ad];
                Al[mt] = *(const bf8*)&vbl[ad];
            }
            #pragma unroll
            for (int nt = 0; nt < 2; ++nt) {
                int ad = ((nh * 2 + nt) * 16 + col) * 72 + kk * 32 + qo8;
                Bh[nt] = *(const bf8*)&PTh[ad];
                Bl[nt] = *(const bf8*)&PTl[ad];
            }
            #pragma unroll
            for (int mt = 0; mt < 2; ++mt)
                #pragma unroll
                for (int nt = 0; nt < 2; ++nt) {
                    av[mt][nt] = MFMA(Ah[mt], Bh[nt], av[mt][nt]);
                    av[mt][nt] = MFMA(Ah[mt], Bl[nt], av[mt][nt]);
                    av[mt][nt] = MFMA(Al[mt], Bh[nt], av[mt][nt]);
                }
        }
        #pragma unroll
        for (int nt = 0; nt < 2; ++nt) {
            int j = (nh * 2 + nt) * 16 + col;
            #pragma unroll
            for (int mt = 0; mt < 2; ++mt) {
                int c0 = (mh * 2 + mt) * 16 + quad * 4;
                #pragma unroll
                for (int rp = 0; rp < 2; ++rp) {
                    unsigned hw, lw; bsplit2(av[mt][nt][2 * rp], av[mt][nt][2 * rp + 1], hw, lw);
                    *(unsigned*)&XTh[j * 72 + c0 + 2 * rp] = hw;
                    *(unsigned*)&XTl[j * 72 + c0 + 2 * rp] = lw;
                }
            }
        }
    }
    __syncthreads();   // (7)

    // ---- P7: MFMA proj conv = 9 shifted GEMMs. M=p, N=oc, K=ic ----
    {
        f32x4 ap[2][2];
        #pragma unroll
        for (int mt = 0; mt < 2; ++mt)
            #pragma unroll
            for (int nt = 0; nt < 2; ++nt) ap[mt][nt] = (f32x4){0.f, 0.f, 0.f, 0.f};
        const int smc = col & 7;
        #pragma unroll 1
        for (int tap = 0; tap < 9; ++tap) {
            int dy = (tap >= 6) ? 1 : ((tap >= 3) ? 0 : -1);
            int dx = tap - (dy + 1) * 3 - 1;
            int ra[2];
            #pragma unroll
            for (int mt = 0; mt < 2; ++mt) {
                int rr = (mh * 2 + mt) * 2 + (col >> 3) + dy;
                int ss = smc + dx;
                bool ok = ((unsigned)rr < 8u) && ((unsigned)ss < 8u);
                ra[mt] = (ok ? (rr * 8 + ss) : 64) * 72;   // row 64 = zeros
            }
            #pragma unroll
            for (int kk = 0; kk < 2; ++kk) {
                bf8 Bh[2], Bl[2], Ah[2], Al[2];
                #pragma unroll
                for (int nt = 0; nt < 2; ++nt) {
                    int bi = (((tap * 2 + kk) * 4 + (nh * 2 + nt)) * 64 + lane) * 8;
                    Bh[nt] = *(const bf8*)&bph[bi];
                    Bl[nt] = *(const bf8*)&bpl[bi];
                }
                #pragma unroll
                for (int mt = 0; mt < 2; ++mt) {
                    int ad = ra[mt] + kk * 32 + qo8;
                    Ah[mt] = *(const bf8*)&XTh[ad];
                    Al[mt] = *(const bf8*)&XTl[ad];
                }
                #pragma unroll
                for (int mt = 0; mt < 2; ++mt)
                    #pragma unroll
                    for (int nt = 0; nt < 2; ++nt) {
                        ap[mt][nt] = MFMA(Ah[mt], Bh[nt], ap[mt][nt]);
                        ap[mt][nt] = MFMA(Ah[mt], Bl[nt], ap[mt][nt]);
                        ap[mt][nt] = MFMA(Al[mt], Bh[nt], ap[mt][nt]);
                    }
            }
        }
        #pragma unroll
        for (int nt = 0; nt < 2; ++nt) {
            int oc = (nh * 2 + nt) * 16 + col;
            #pragma unroll
            for (int mt = 0; mt < 2; ++mt) {
                int p0 = (mh * 2 + mt) * 16 + quad * 4;
                *(f32x4*)&projo[pswz(oc, p0)] = ap[mt][nt];
            }
        }
    }
    __syncthreads();   // (8)

    // ---- P8: window reverse + roll, coalesced image-order stores ----
    #pragma unroll
    for (int k = 0; k < 16; ++k) {
        int o = tid + k * 256;
        int hi = o >> 11, r = (o >> 8) & 7, lo = (o >> 3) & 31, s = o & 7;
        int c2 = hi * 32 + lo;
        float v = projo[pswz(c2, r * 8 + s)];
        int h2 = t * 16 + hi * 8 + r, w2 = lo * 8 + s;
        out[base + (size_t)((h2 + roll) & 255) * 256 + ((w2 + roll) & 255)] = v;
    }
}

extern "C" void kernel_launch(void* const* d_in, const int* in_sizes, int n_in,
                              void* d_out, int out_size, void* d_ws, size_t ws_size,
                              hipStream_t stream)
{
    const float* x      = (const float*)d_in[0];
    const float* wqkv0  = (const float*)d_in[1];
    const float* wdw0   = (const float*)d_in[2];
    const float* wproj0 = (const float*)d_in[3];
    const float* wqkv1  = (const float*)d_in[4];
    const float* wdw1   = (const float*)d_in[5];
    const float* wproj1 = (const float*)d_in[6];
    float* out = (float*)d_out;

    float* tmp = (float*)d_ws;                       // 33,554,432 floats (134 MB)
    short* fb  = (short*)(tmp + 33554432);
    short* bq0h = fb;                                // 12288 each
    short* bq0l = fb + 12288;
    short* bq1h = fb + 24576;
    short* bq1l = fb + 36864;
    short* bp0h = fb + 49152;                        // 36864 each
    short* bp0l = fb + 86016;
    short* bp1h = fb + 122880;
    short* bp1l = fb + 159744;

    hipLaunchKernelGGL(k_fq, dim3(24), dim3(512), 0, stream, wqkv0, bq0h, bq0l);
    hipLaunchKernelGGL(k_fq, dim3(24), dim3(512), 0, stream, wqkv1, bq1h, bq1l);
    hipLaunchKernelGGL(k_fp, dim3(72), dim3(512), 0, stream, wproj0, bp0h, bp0l);
    hipLaunchKernelGGL(k_fp, dim3(72), dim3(512), 0, stream, wproj1, bp1h, bp1l);

    // pass 1: x -> tmp (no shift/mask/roll)
    hipLaunchKernelGGL(k_fused, dim3(8192), dim3(256), 0, stream,
                       x, bq0h, bq0l, wdw0, bp0h, bp0l, tmp, 0, 0, 0);
    // pass 2: tmp -> out (shift +4 read, Swin mask, roll +4 write)
    hipLaunchKernelGGL(k_fused, dim3(8192), dim3(256), 0, stream,
                       tmp, bq1h, bq1l, wdw1, bp1h, bp1l, out, 4, 1, 4);
}

// Round 2
// 664.714 us; speedup vs baseline: 1.2776x; 1.1510x over previous
//
#include <hip/hip_runtime.h>

// LocalAttention (Swin scrambled-window variant) — all four GEMMs on MFMA.
// Window map (verified pass R2/R3): n=b*1024+c*16+t ; c2=hi*32+lo ; p=r*8+s ;
// h=16t+8hi+r ; w=8lo+s ; mask index = n&1023.
// l2norm folds into k:  attn[i][j] = sum_c q[c][i] * (k[c][j]*0.125/(nq_c*nk_c)).
// Split-bf16 everywhere: x=hi+lo, D += Ah*Bh + Ah*Bl + Al*Bh (rel err ~2^-18).
//
// R5: 3 blocks/CU via LDS 74KB -> 50.4KB.
//   - q/k/v planes chunked through ONE 17.4KB fp32 scratch (3x P2->DW passes).
//   - dw results stay in regs; dk/dq scatter DIRECTLY to kT/qT (no DWw+TR phases).
//   - bf16 regions: stride 64 shorts, swizzle key xkey(p)=((p>>3)^p)&7. Enumerated:
//     all b128 fragment reads uniform 8 lanes/16B-slot (floor); reg->LDS transposed
//     scatter 2-way (free) with compile-time value indices.
//   - fp32 scratch/projo: stride 68 dwords + granule XOR swizzle (dw stencil uniform).
//   Regions: A[0,16640) XTin->qT->attn-out (65x64 bf16 h/l, row64=zeros)
//            B[16640,34048) scr fp32 64x68 -> vb bf16 -> projo fp32
//            C[34048,50432) kT bf16 -> PT bf16
//   11 barriers; __launch_bounds__(256,3).

typedef __attribute__((ext_vector_type(8))) short bf8;
typedef __attribute__((ext_vector_type(4))) float f32x4;
#define MFMA(a, b, c) __builtin_amdgcn_mfma_f32_16x16x32_bf16(a, b, c, 0, 0, 0)

__device__ __forceinline__ int xkey(int p) { return ((p >> 3) ^ p) & 7; }
// bf16 region: row p (pixel or channel), col c (0..63) -> short index
__device__ __forceinline__ int xswz(int p, int c) { return p * 64 + (c ^ (xkey(p) << 3)); }
// fp32 region: channel ch, pixel p -> dword index (stride 68)
__device__ __forceinline__ int pswz68(int ch, int p) {
    return ch * 68 + (p ^ (((ch >> 1) & 7) << 2));
}

__device__ __forceinline__ void bsplit(float f, short& h, short& l) {
    unsigned u = __float_as_uint(f);
    unsigned hb = (u + 0x7FFFu + ((u >> 16) & 1u)) >> 16;
    float hf = __uint_as_float(hb << 16);
    float r = f - hf;
    unsigned u2 = __float_as_uint(r);
    unsigned lb = (u2 + 0x7FFFu + ((u2 >> 16) & 1u)) >> 16;
    h = (short)hb; l = (short)lb;
}
__device__ __forceinline__ void bsplit2(float a, float b, unsigned& hw, unsigned& lw) {
    short ha, la, hb_, lb_;
    bsplit(a, ha, la); bsplit(b, hb_, lb_);
    hw = (unsigned)(unsigned short)ha | ((unsigned)(unsigned short)hb_ << 16);
    lw = (unsigned)(unsigned short)la | ((unsigned)(unsigned short)lb_ << 16);
}

// ---- qkv 1x1 weight fragments: [kk(2)][tt(12)][lane(64)][j(8)]  B[n=oc][k=ic] ----
__global__ void k_fq(const float* __restrict__ wq, short* __restrict__ oh, short* __restrict__ ol) {
    int bx = blockIdx.x;                 // kk*12 + tt
    int kk = bx / 12, tt = bx % 12;
    int tid = threadIdx.x;               // 512
    int lane = tid >> 3, j = tid & 7;
    int oc = tt * 16 + (lane & 15);
    int ic = kk * 32 + ((lane >> 4) << 3) + j;
    short h, l; bsplit(wq[oc * 64 + ic], h, l);
    oh[bx * 512 + tid] = h; ol[bx * 512 + tid] = l;
}
// ---- proj 3x3 weight fragments: [tap(9)][kk(2)][tt(4)][lane(64)][j(8)] ----
__global__ void k_fp(const float* __restrict__ wp, short* __restrict__ oh, short* __restrict__ ol) {
    int bx = blockIdx.x;                 // tap*8 + kk*4 + tt
    int tap = bx >> 3, kk = (bx >> 2) & 1, tt = bx & 3;
    int tid = threadIdx.x;
    int lane = tid >> 3, j = tid & 7;
    int oc = tt * 16 + (lane & 15);
    int ic = kk * 32 + ((lane >> 4) << 3) + j;
    short h, l; bsplit(wp[(oc * 64 + ic) * 9 + tap], h, l);
    oh[bx * 512 + tid] = h; ol[bx * 512 + tid] = l;
}

// dw3x3 for a channel pair (local ch 0..63 in scr), one output row, zero pad.
__device__ __forceinline__ void dw_pair(const float* scr, const float* wd9,
                                        int ch0, int row, float o[2][8]) {
    #pragma unroll
    for (int chi = 0; chi < 2; ++chi) {
        int ch = ch0 + chi;
        const float* wd = wd9 + ch * 9;
        float w9[9];
        #pragma unroll
        for (int tp = 0; tp < 9; ++tp) w9[tp] = wd[tp];
        float e[3][10];
        #pragma unroll
        for (int k3 = 0; k3 < 3; ++k3) {
            int rr = row - 1 + k3;
            e[k3][0] = 0.f; e[k3][9] = 0.f;
            if ((unsigned)rr < 8u) {
                float4 a = *(const float4*)&scr[pswz68(ch, rr * 8)];
                float4 b = *(const float4*)&scr[pswz68(ch, rr * 8 + 4)];
                e[k3][1] = a.x; e[k3][2] = a.y; e[k3][3] = a.z; e[k3][4] = a.w;
                e[k3][5] = b.x; e[k3][6] = b.y; e[k3][7] = b.z; e[k3][8] = b.w;
            } else {
                #pragma unroll
                for (int q2 = 1; q2 < 9; ++q2) e[k3][q2] = 0.f;
            }
        }
        #pragma unroll
        for (int s = 0; s < 8; ++s) {
            float a = 0.f;
            #pragma unroll
            for (int k3 = 0; k3 < 3; ++k3)
                #pragma unroll
                for (int dx = 0; dx < 3; ++dx)
                    a = fmaf(w9[k3 * 3 + dx], e[k3][s + dx], a);
            o[chi][s] = a;
        }
    }
}

// P2 chunk: 64px x 64oc x 64ic MFMA 1x1, XTin -> scr. chunk 0=q,1=k,2=v.
__device__ __forceinline__ void p2_chunk(const short* XTh, const short* XTl,
                                         const short* bqh, const short* bql,
                                         float* scr, int chunk,
                                         int mh, int nh, int col, int quad, int qo8, int lane)
{
    f32x4 acc[2][2];
    #pragma unroll
    for (int mt = 0; mt < 2; ++mt)
        #pragma unroll
        for (int nt = 0; nt < 2; ++nt) acc[mt][nt] = (f32x4){0.f, 0.f, 0.f, 0.f};
    #pragma unroll
    for (int kk = 0; kk < 2; ++kk) {
        bf8 Ah[2], Al[2];
        #pragma unroll
        for (int mt = 0; mt < 2; ++mt) {
            int row = (mh * 2 + mt) * 16 + col;
            int ad = row * 64 + ((kk * 32 + qo8) ^ (xkey(row) << 3));
            Ah[mt] = *(const bf8*)&XTh[ad];
            Al[mt] = *(const bf8*)&XTl[ad];
        }
        #pragma unroll
        for (int nt = 0; nt < 2; ++nt) {
            int tt = chunk * 4 + nh * 2 + nt;
            bf8 Bh = *(const bf8*)&bqh[((kk * 12 + tt) * 64 + lane) * 8];
            bf8 Bl = *(const bf8*)&bql[((kk * 12 + tt) * 64 + lane) * 8];
            #pragma unroll
            for (int mt = 0; mt < 2; ++mt) {
                acc[mt][nt] = MFMA(Ah[mt], Bh, acc[mt][nt]);
                acc[mt][nt] = MFMA(Ah[mt], Bl, acc[mt][nt]);
                acc[mt][nt] = MFMA(Al[mt], Bh, acc[mt][nt]);
            }
        }
    }
    #pragma unroll
    for (int nt = 0; nt < 2; ++nt) {
        int oc = (nh * 2 + nt) * 16 + col;
        #pragma unroll
        for (int mt = 0; mt < 2; ++mt) {
            int p0 = (mh * 2 + mt) * 16 + quad * 4;
            *(f32x4*)&scr[pswz68(oc, p0)] = acc[mt][nt];
        }
    }
}

__global__ __launch_bounds__(256, 3)
void k_fused(const float* __restrict__ in,
             const short* __restrict__ bqh, const short* __restrict__ bql,
             const float* __restrict__ wdw,
             const short* __restrict__ bph, const short* __restrict__ bpl,
             float* __restrict__ out, int shift, int use_mask, int roll)
{
    __shared__ __align__(16) char smem[50432];
    short* XTh = (short*)smem;                       // A: XTin -> qT -> attn-out
    short* XTl = (short*)(smem + 8320);
    float* scr = (float*)(smem + 16640);             // B: fp32 planes (stride 68)
    short* vbh = (short*)(smem + 16640);             // B: vb after DWv
    short* vbl = (short*)(smem + 24832);
    float* projo = (float*)(smem + 16640);           // B: after P6
    short* kTh = (short*)(smem + 34048);             // C: kT -> PT
    short* kTl = (short*)(smem + 42240);
    short* PTh = kTh;
    short* PTl = kTl;

    const int tid = threadIdx.x, lane = tid & 63, wv = tid >> 6;
    const int col = lane & 15, quad = lane >> 4, qo8 = quad * 8;
    const int mh = wv & 1, nh = wv >> 1;
    const int cp = tid >> 3, rrow = tid & 7;
    const int n = blockIdx.x;
    const int b = n >> 10, c = (n >> 4) & 63, t = n & 15;
    const size_t base = ((size_t)(b * 64 + c)) << 16;

    // ---- P1: load window (shift folded), split, XTin[p][c2] ----
    #pragma unroll
    for (int k = 0; k < 16; ++k) {
        int o = tid + k * 256;
        int hi = o >> 11, r = (o >> 8) & 7, lo = (o >> 3) & 31, s = o & 7;
        int h2 = t * 16 + hi * 8 + r, w2 = lo * 8 + s;
        float v = in[base + (size_t)((h2 + shift) & 255) * 256 + ((w2 + shift) & 255)];
        short hh, ll; bsplit(v, hh, ll);
        int ad = xswz(r * 8 + s, hi * 32 + lo);
        XTh[ad] = hh; XTl[ad] = ll;
    }
    __syncthreads();   // (1)

    // ---- P2q -> scr ----
    p2_chunk(XTh, XTl, bqh, bql, scr, 0, mh, nh, col, quad, qo8, lane);
    __syncthreads();   // (2)

    // ---- DWq: dw3x3 q -> dq regs + per-channel norms ----
    float dq[2][8], nq[2];
    dw_pair(scr, wdw, 2 * cp, rrow, dq);
    #pragma unroll
    for (int chi = 0; chi < 2; ++chi) {
        float ss = 0.f;
        #pragma unroll
        for (int s = 0; s < 8; ++s) ss = fmaf(dq[chi][s], dq[chi][s], ss);
        ss += __shfl_xor(ss, 1); ss += __shfl_xor(ss, 2); ss += __shfl_xor(ss, 4);
        nq[chi] = fmaxf(sqrtf(ss), 1e-12f);
    }
    __syncthreads();   // (3) scr reads done

    // ---- P2k -> scr ----
    p2_chunk(XTh, XTl, bqh, bql, scr, 1, mh, nh, col, quad, qo8, lane);
    __syncthreads();   // (4)

    // ---- DWk: dw3x3 k -> regs, fold 0.125/(nq*nk), scatter -> kT ----
    {
        float dk[2][8];
        dw_pair(scr, wdw + 64 * 9, 2 * cp, rrow, dk);
        #pragma unroll
        for (int chi = 0; chi < 2; ++chi) {
            float ss = 0.f;
            #pragma unroll
            for (int s = 0; s < 8; ++s) ss = fmaf(dk[chi][s], dk[chi][s], ss);
            ss += __shfl_xor(ss, 1); ss += __shfl_xor(ss, 2); ss += __shfl_xor(ss, 4);
            float nk = fmaxf(sqrtf(ss), 1e-12f);
            float sc = 0.125f / (nq[chi] * nk);
            #pragma unroll
            for (int s = 0; s < 8; ++s) dk[chi][s] *= sc;
        }
        #pragma unroll
        for (int s0 = 0; s0 < 8; ++s0) {       // reg->LDS transposed scatter, 2-way free
            unsigned hw, lw; bsplit2(dk[0][s0], dk[1][s0], hw, lw);
            int ad = xswz(rrow * 8 + s0, 2 * cp);
            *(unsigned*)&kTh[ad] = hw; *(unsigned*)&kTl[ad] = lw;
        }
    }
    __syncthreads();   // (5) scr reads done

    // ---- P2v -> scr (last XTin reader) ----
    p2_chunk(XTh, XTl, bqh, bql, scr, 2, mh, nh, col, quad, qo8, lane);
    __syncthreads();   // (6)

    // ---- DWv -> dv regs ; scatter dq -> qT (A free now) ; zero A row 64 ----
    float dv[2][8];
    dw_pair(scr, wdw + 128 * 9, 2 * cp, rrow, dv);
    #pragma unroll
    for (int s0 = 0; s0 < 8; ++s0) {
        unsigned hw, lw; bsplit2(dq[0][s0], dq[1][s0], hw, lw);
        int ad = xswz(rrow * 8 + s0, 2 * cp);
        *(unsigned*)&XTh[ad] = hw; *(unsigned*)&XTl[ad] = lw;
    }
    if (tid < 32) {
        *(unsigned*)&XTh[4096 + 2 * tid] = 0u;
        *(unsigned*)&XTl[4096 + 2 * tid] = 0u;
    }
    __syncthreads();   // (7) scr reads done, qT/kT ready

    // ---- VB: dv regs -> vb[c][i] (B region) ----
    #pragma unroll
    for (int chi = 0; chi < 2; ++chi) {
        unsigned hw[4], lw[4];
        #pragma unroll
        for (int q2 = 0; q2 < 4; ++q2) bsplit2(dv[chi][2 * q2], dv[chi][2 * q2 + 1], hw[q2], lw[q2]);
        int ch = 2 * cp + chi;
        int ad = ch * 64 + ((rrow ^ xkey(ch)) << 3);
        *(uint4*)&vbh[ad] = (uint4){hw[0], hw[1], hw[2], hw[3]};
        *(uint4*)&vbl[ad] = (uint4){lw[0], lw[1], lw[2], lw[3]};
    }

    // ---- P5: MFMA QK^T (M=i rows wv*16.., N=j all 64, K=c) + mask + softmax ----
    f32x4 at[4];
    #pragma unroll
    for (int nt = 0; nt < 4; ++nt) at[nt] = (f32x4){0.f, 0.f, 0.f, 0.f};
    {
        bf8 Ah[2], Al[2];
        #pragma unroll
        for (int kk = 0; kk < 2; ++kk) {
            int row = wv * 16 + col;
            int ad = row * 64 + ((kk * 32 + qo8) ^ (xkey(row) << 3));
            Ah[kk] = *(const bf8*)&XTh[ad];   // qT
            Al[kk] = *(const bf8*)&XTl[ad];
        }
        #pragma unroll
        for (int kk = 0; kk < 2; ++kk)
            #pragma unroll
            for (int nt = 0; nt < 4; ++nt) {
                int rowB = nt * 16 + col;
                int ad = rowB * 64 + ((kk * 32 + qo8) ^ (xkey(rowB) << 3));
                bf8 Bh = *(const bf8*)&kTh[ad];
                bf8 Bl = *(const bf8*)&kTl[ad];
                at[nt] = MFMA(Ah[kk], Bh, at[nt]);
                at[nt] = MFMA(Ah[kk], Bl, at[nt]);
                at[nt] = MFMA(Al[kk], Bh, at[nt]);
            }
    }
    if (use_mask) {
        const int widx = n & 1023;
        const int hn_m = widx >> 5, wn_m = widx & 31;
        #pragma unroll
        for (int nt = 0; nt < 4; ++nt) {
            int j = nt * 16 + col;
            int rj = ((hn_m == 31) ? (((j >> 3) < 4) ? 1 : 2) : 0) * 3
                   + ((wn_m == 31) ? (((j & 7) < 4) ? 1 : 2) : 0);
            #pragma unroll
            for (int rg = 0; rg < 4; ++rg) {
                int i = wv * 16 + quad * 4 + rg;
                int ri = ((hn_m == 31) ? (((i >> 3) < 4) ? 1 : 2) : 0) * 3
                       + ((wn_m == 31) ? (((i & 7) < 4) ? 1 : 2) : 0);
                if (ri != rj) at[nt][rg] = at[nt][rg] - 100.f;
            }
        }
    }
    float Pv[4][4];
    #pragma unroll
    for (int rg = 0; rg < 4; ++rg) {
        float m = fmaxf(fmaxf(at[0][rg], at[1][rg]), fmaxf(at[2][rg], at[3][rg]));
        m = fmaxf(m, __shfl_xor(m, 1)); m = fmaxf(m, __shfl_xor(m, 2));
        m = fmaxf(m, __shfl_xor(m, 4)); m = fmaxf(m, __shfl_xor(m, 8));
        float e0 = __expf(at[0][rg] - m), e1 = __expf(at[1][rg] - m);
        float e2 = __expf(at[2][rg] - m), e3 = __expf(at[3][rg] - m);
        float s = e0 + e1 + e2 + e3;
        s += __shfl_xor(s, 1); s += __shfl_xor(s, 2);
        s += __shfl_xor(s, 4); s += __shfl_xor(s, 8);
        float is = 1.0f / s;
        Pv[0][rg] = e0 * is; Pv[1][rg] = e1 * is; Pv[2][rg] = e2 * is; Pv[3][rg] = e3 * is;
    }
    __syncthreads();   // (8) qT/kT reads done

    // ---- PT write: PT[j][i] (overlays kT) ----
    #pragma unroll
    for (int nt = 0; nt < 4; ++nt) {
        int j = nt * 16 + col;
        #pragma unroll
        for (int rp = 0; rp < 2; ++rp) {
            unsigned hw, lw; bsplit2(Pv[nt][2 * rp], Pv[nt][2 * rp + 1], hw, lw);
            int i0 = wv * 16 + quad * 4 + 2 * rp;
            int ad = j * 64 + (i0 ^ (xkey(j) << 3));
            *(unsigned*)&PTh[ad] = hw; *(unsigned*)&PTl[ad] = lw;
        }
    }
    __syncthreads();   // (9)

    // ---- P6: MFMA V*A. M=c, N=j, K=i. A=vb[c][i], B=PT[j][i]. D -> XT[p=j][c] ----
    {
        f32x4 av[2][2];
        #pragma unroll
        for (int mt = 0; mt < 2; ++mt)
            #pragma unroll
            for (int nt = 0; nt < 2; ++nt) av[mt][nt] = (f32x4){0.f, 0.f, 0.f, 0.f};
        #pragma unroll
        for (int kk = 0; kk < 2; ++kk) {
            bf8 Ah[2], Al[2], Bh[2], Bl[2];
            #pragma unroll
            for (int mt = 0; mt < 2; ++mt) {
                int row = (mh * 2 + mt) * 16 + col;
                int ad = row * 64 + ((kk * 32 + qo8) ^ (xkey(row) << 3));
                Ah[mt] = *(const bf8*)&vbh[ad];
                Al[mt] = *(const bf8*)&vbl[ad];
            }
            #pragma unroll
            for (int nt = 0; nt < 2; ++nt) {
                int rowB = (nh * 2 + nt) * 16 + col;
                int ad = rowB * 64 + ((kk * 32 + qo8) ^ (xkey(rowB) << 3));
                Bh[nt] = *(const bf8*)&PTh[ad];
                Bl[nt] = *(const bf8*)&PTl[ad];
            }
            #pragma unroll
            for (int mt = 0; mt < 2; ++mt)
                #pragma unroll
                for (int nt = 0; nt < 2; ++nt) {
                    av[mt][nt] = MFMA(Ah[mt], Bh[nt], av[mt][nt]);
                    av[mt][nt] = MFMA(Ah[mt], Bl[nt], av[mt][nt]);
                    av[mt][nt] = MFMA(Al[mt], Bh[nt], av[mt][nt]);
                }
        }
        #pragma unroll
        for (int nt = 0; nt < 2; ++nt) {
            int j = (nh * 2 + nt) * 16 + col;
            #pragma unroll
            for (int mt = 0; mt < 2; ++mt) {
                int c0 = (mh * 2 + mt) * 16 + quad * 4;
                #pragma unroll
                for (int rp = 0; rp < 2; ++rp) {
                    unsigned hw, lw; bsplit2(av[mt][nt][2 * rp], av[mt][nt][2 * rp + 1], hw, lw);
                    int ad = j * 64 + ((c0 + 2 * rp) ^ (xkey(j) << 3));
                    *(unsigned*)&XTh[ad] = hw;
                    *(unsigned*)&XTl[ad] = lw;
                }
            }
        }
    }
    __syncthreads();   // (10)

    // ---- P7: MFMA proj conv = 9 shifted GEMMs. M=p, N=oc, K=ic ----
    {
        f32x4 ap[2][2];
        #pragma unroll
        for (int mt = 0; mt < 2; ++mt)
            #pragma unroll
            for (int nt = 0; nt < 2; ++nt) ap[mt][nt] = (f32x4){0.f, 0.f, 0.f, 0.f};
        const int smc = col & 7;
        #pragma unroll 1
        for (int tap = 0; tap < 9; ++tap) {
            int dy = (tap >= 6) ? 1 : ((tap >= 3) ? 0 : -1);
            int dx = tap - (dy + 1) * 3 - 1;
            int ra[2];
            #pragma unroll
            for (int mt = 0; mt < 2; ++mt) {
                int rr = (mh * 2 + mt) * 2 + (col >> 3) + dy;
                int ss = smc + dx;
                bool ok = ((unsigned)rr < 8u) && ((unsigned)ss < 8u);
                ra[mt] = ok ? (rr * 8 + ss) : 64;   // row 64 = zeros
            }
            #pragma unroll
            for (int kk = 0; kk < 2; ++kk) {
                bf8 Bh[2], Bl[2], Ah[2], Al[2];
                #pragma unroll
                for (int nt = 0; nt < 2; ++nt) {
                    int bi = (((tap * 2 + kk) * 4 + (nh * 2 + nt)) * 64 + lane) * 8;
                    Bh[nt] = *(const bf8*)&bph[bi];
                    Bl[nt] = *(const bf8*)&bpl[bi];
                }
                #pragma unroll
                for (int mt = 0; mt < 2; ++mt) {
                    int ad = ra[mt] * 64 + ((kk * 32 + qo8) ^ (xkey(ra[mt]) << 3));
                    Ah[mt] = *(const bf8*)&XTh[ad];
                    Al[mt] = *(const bf8*)&XTl[ad];
                }
                #pragma unroll
                for (int mt = 0; mt < 2; ++mt)
                    #pragma unroll
                    for (int nt = 0; nt < 2; ++nt) {
                        ap[mt][nt] = MFMA(Ah[mt], Bh[nt], ap[mt][nt]);
                        ap[mt][nt] = MFMA(Ah[mt], Bl[nt], ap[mt][nt]);
                        ap[mt][nt] = MFMA(Al[mt], Bh[nt], ap[mt][nt]);
                    }
            }
        }
        #pragma unroll
        for (int nt = 0; nt < 2; ++nt) {
            int oc = (nh * 2 + nt) * 16 + col;
            #pragma unroll
            for (int mt = 0; mt < 2; ++mt) {
                int p0 = (mh * 2 + mt) * 16 + quad * 4;
                *(f32x4*)&projo[pswz68(oc, p0)] = ap[mt][nt];
            }
        }
    }
    __syncthreads();   // (11)

    // ---- P8: window reverse + roll, coalesced image-order stores ----
    #pragma unroll
    for (int k = 0; k < 16; ++k) {
        int o = tid + k * 256;
        int hi = o >> 11, r = (o >> 8) & 7, lo = (o >> 3) & 31, s = o & 7;
        int c2 = hi * 32 + lo;
        float v = projo[pswz68(c2, r * 8 + s)];
        int h2 = t * 16 + hi * 8 + r, w2 = lo * 8 + s;
        out[base + (size_t)((h2 + roll) & 255) * 256 + ((w2 + roll) & 255)] = v;
    }
}

extern "C" void kernel_launch(void* const* d_in, const int* in_sizes, int n_in,
                              void* d_out, int out_size, void* d_ws, size_t ws_size,
                              hipStream_t stream)
{
    const float* x      = (const float*)d_in[0];
    const float* wqkv0  = (const float*)d_in[1];
    const float* wdw0   = (const float*)d_in[2];
    const float* wproj0 = (const float*)d_in[3];
    const float* wqkv1  = (const float*)d_in[4];
    const float* wdw1   = (const float*)d_in[5];
    const float* wproj1 = (const float*)d_in[6];
    float* out = (float*)d_out;

    float* tmp = (float*)d_ws;                       // 33,554,432 floats (134 MB)
    short* fb  = (short*)(tmp + 33554432);
    short* bq0h = fb;                                // 12288 each
    short* bq0l = fb + 12288;
    short* bq1h = fb + 24576;
    short* bq1l = fb + 36864;
    short* bp0h = fb + 49152;                        // 36864 each
    short* bp0l = fb + 86016;
    short* bp1h = fb + 122880;
    short* bp1l = fb + 159744;

    hipLaunchKernelGGL(k_fq, dim3(24), dim3(512), 0, stream, wqkv0, bq0h, bq0l);
    hipLaunchKernelGGL(k_fq, dim3(24), dim3(512), 0, stream, wqkv1, bq1h, bq1l);
    hipLaunchKernelGGL(k_fp, dim3(72), dim3(512), 0, stream, wproj0, bp0h, bp0l);
    hipLaunchKernelGGL(k_fp, dim3(72), dim3(512), 0, stream, wproj1, bp1h, bp1l);

    // pass 1: x -> tmp (no shift/mask/roll)
    hipLaunchKernelGGL(k_fused, dim3(8192), dim3(256), 0, stream,
                       x, bq0h, bq0l, wdw0, bp0h, bp0l, tmp, 0, 0, 0);
    // pass 2: tmp -> out (shift +4 read, Swin mask, roll +4 write)
    hipLaunchKernelGGL(k_fused, dim3(8192), dim3(256), 0, stream,
                       tmp, bq1h, bq1l, wdw1, bp1h, bp1l, out, 4, 1, 4);
}

// Round 3
// 635.637 us; speedup vs baseline: 1.3360x; 1.0457x over previous
//
#include <hip/hip_runtime.h>

// LocalAttention (Swin scrambled-window variant) — all four GEMMs on MFMA.
// Window map (verified pass R2/R3): n=b*1024+c*16+t ; c2=hi*32+lo ; p=r*8+s ;
// h=16t+8hi+r ; w=8lo+s ; mask index = n&1023.
// l2norm folds into k:  attn[i][j] = sum_c q[c][i] * (k[c][j]*0.125/(nq_c*nk_c)).
// Split-bf16 everywhere: x=hi+lo, D += Ah*Bh + Ah*Bl + Al*Bh (rel err ~2^-18).
//
// R5: 3 blocks/CU via LDS 74KB -> 50.4KB (chunked scratch, reg->LDS scatters).
// R6: bsplit2 via v_cvt_pk_bf16_f32 (RNE, same rounding as the old bit-trick):
//     6 VALU ops vs ~16. P1 loads paired so all splits go through cvt_pk.
//     Kernel was issue-port bound (VALUBusy 59 + MfmaUtil 29 ~= 88%).
//
//   Regions: A[0,16640) XTin->qT->attn-out (65x64 bf16 h/l, row64=zeros)
//            B[16640,34048) scr fp32 64x68 -> vb bf16 -> projo fp32
//            C[34048,50432) kT bf16 -> PT bf16
//   11 barriers; __launch_bounds__(256,3).

typedef __attribute__((ext_vector_type(8))) short bf8;
typedef __attribute__((ext_vector_type(4))) float f32x4;
#define MFMA(a, b, c) __builtin_amdgcn_mfma_f32_16x16x32_bf16(a, b, c, 0, 0, 0)

__device__ __forceinline__ int xkey(int p) { return ((p >> 3) ^ p) & 7; }
// bf16 region: row p (pixel or channel), col c (0..63) -> short index
__device__ __forceinline__ int xswz(int p, int c) { return p * 64 + (c ^ (xkey(p) << 3)); }
// fp32 region: channel ch, pixel p -> dword index (stride 68)
__device__ __forceinline__ int pswz68(int ch, int p) {
    return ch * 68 + (p ^ (((ch >> 1) & 7) << 2));
}

// packed 2xf32 -> 2xbf16 (RNE). No builtin on gfx950 — inline asm (T12/m240).
__device__ __forceinline__ unsigned cvtpk(float a, float b) {
    unsigned r;
    asm("v_cvt_pk_bf16_f32 %0, %1, %2" : "=v"(r) : "v"(a), "v"(b));
    return r;
}

__device__ __forceinline__ void bsplit(float f, short& h, short& l) {
    unsigned u = __float_as_uint(f);
    unsigned hb = (u + 0x7FFFu + ((u >> 16) & 1u)) >> 16;
    float hf = __uint_as_float(hb << 16);
    float r = f - hf;
    unsigned u2 = __float_as_uint(r);
    unsigned lb = (u2 + 0x7FFFu + ((u2 >> 16) & 1u)) >> 16;
    h = (short)hb; l = (short)lb;
}
// a in low half, b in high half. hi = RNE-bf16(x); lo = RNE-bf16(x - hi).
__device__ __forceinline__ void bsplit2(float a, float b, unsigned& hw, unsigned& lw) {
    hw = cvtpk(a, b);
    float ra = a - __uint_as_float(hw << 16);
    float rb = b - __uint_as_float(hw & 0xFFFF0000u);
    lw = cvtpk(ra, rb);
}

// ---- qkv 1x1 weight fragments: [kk(2)][tt(12)][lane(64)][j(8)]  B[n=oc][k=ic] ----
__global__ void k_fq(const float* __restrict__ wq, short* __restrict__ oh, short* __restrict__ ol) {
    int bx = blockIdx.x;                 // kk*12 + tt
    int kk = bx / 12, tt = bx % 12;
    int tid = threadIdx.x;               // 512
    int lane = tid >> 3, j = tid & 7;
    int oc = tt * 16 + (lane & 15);
    int ic = kk * 32 + ((lane >> 4) << 3) + j;
    short h, l; bsplit(wq[oc * 64 + ic], h, l);
    oh[bx * 512 + tid] = h; ol[bx * 512 + tid] = l;
}
// ---- proj 3x3 weight fragments: [tap(9)][kk(2)][tt(4)][lane(64)][j(8)] ----
__global__ void k_fp(const float* __restrict__ wp, short* __restrict__ oh, short* __restrict__ ol) {
    int bx = blockIdx.x;                 // tap*8 + kk*4 + tt
    int tap = bx >> 3, kk = (bx >> 2) & 1, tt = bx & 3;
    int tid = threadIdx.x;
    int lane = tid >> 3, j = tid & 7;
    int oc = tt * 16 + (lane & 15);
    int ic = kk * 32 + ((lane >> 4) << 3) + j;
    short h, l; bsplit(wp[(oc * 64 + ic) * 9 + tap], h, l);
    oh[bx * 512 + tid] = h; ol[bx * 512 + tid] = l;
}

// dw3x3 for a channel pair (local ch 0..63 in scr), one output row, zero pad.
__device__ __forceinline__ void dw_pair(const float* scr, const float* wd9,
                                        int ch0, int row, float o[2][8]) {
    #pragma unroll
    for (int chi = 0; chi < 2; ++chi) {
        int ch = ch0 + chi;
        const float* wd = wd9 + ch * 9;
        float w9[9];
        #pragma unroll
        for (int tp = 0; tp < 9; ++tp) w9[tp] = wd[tp];
        float e[3][10];
        #pragma unroll
        for (int k3 = 0; k3 < 3; ++k3) {
            int rr = row - 1 + k3;
            e[k3][0] = 0.f; e[k3][9] = 0.f;
            if ((unsigned)rr < 8u) {
                float4 a = *(const float4*)&scr[pswz68(ch, rr * 8)];
                float4 b = *(const float4*)&scr[pswz68(ch, rr * 8 + 4)];
                e[k3][1] = a.x; e[k3][2] = a.y; e[k3][3] = a.z; e[k3][4] = a.w;
                e[k3][5] = b.x; e[k3][6] = b.y; e[k3][7] = b.z; e[k3][8] = b.w;
            } else {
                #pragma unroll
                for (int q2 = 1; q2 < 9; ++q2) e[k3][q2] = 0.f;
            }
        }
        #pragma unroll
        for (int s = 0; s < 8; ++s) {
            float a = 0.f;
            #pragma unroll
            for (int k3 = 0; k3 < 3; ++k3)
                #pragma unroll
                for (int dx = 0; dx < 3; ++dx)
                    a = fmaf(w9[k3 * 3 + dx], e[k3][s + dx], a);
            o[chi][s] = a;
        }
    }
}

// P2 chunk: 64px x 64oc x 64ic MFMA 1x1, XTin -> scr. chunk 0=q,1=k,2=v.
__device__ __forceinline__ void p2_chunk(const short* XTh, const short* XTl,
                                         const short* bqh, const short* bql,
                                         float* scr, int chunk,
                                         int mh, int nh, int col, int quad, int qo8, int lane)
{
    f32x4 acc[2][2];
    #pragma unroll
    for (int mt = 0; mt < 2; ++mt)
        #pragma unroll
        for (int nt = 0; nt < 2; ++nt) acc[mt][nt] = (f32x4){0.f, 0.f, 0.f, 0.f};
    #pragma unroll
    for (int kk = 0; kk < 2; ++kk) {
        bf8 Ah[2], Al[2];
        #pragma unroll
        for (int mt = 0; mt < 2; ++mt) {
            int row = (mh * 2 + mt) * 16 + col;
            int ad = row * 64 + ((kk * 32 + qo8) ^ (xkey(row) << 3));
            Ah[mt] = *(const bf8*)&XTh[ad];
            Al[mt] = *(const bf8*)&XTl[ad];
        }
        #pragma unroll
        for (int nt = 0; nt < 2; ++nt) {
            int tt = chunk * 4 + nh * 2 + nt;
            bf8 Bh = *(const bf8*)&bqh[((kk * 12 + tt) * 64 + lane) * 8];
            bf8 Bl = *(const bf8*)&bql[((kk * 12 + tt) * 64 + lane) * 8];
            #pragma unroll
            for (int mt = 0; mt < 2; ++mt) {
                acc[mt][nt] = MFMA(Ah[mt], Bh, acc[mt][nt]);
                acc[mt][nt] = MFMA(Ah[mt], Bl, acc[mt][nt]);
                acc[mt][nt] = MFMA(Al[mt], Bh, acc[mt][nt]);
            }
        }
    }
    #pragma unroll
    for (int nt = 0; nt < 2; ++nt) {
        int oc = (nh * 2 + nt) * 16 + col;
        #pragma unroll
        for (int mt = 0; mt < 2; ++mt) {
            int p0 = (mh * 2 + mt) * 16 + quad * 4;
            *(f32x4*)&scr[pswz68(oc, p0)] = acc[mt][nt];
        }
    }
}

__global__ __launch_bounds__(256, 3)
void k_fused(const float* __restrict__ in,
             const short* __restrict__ bqh, const short* __restrict__ bql,
             const float* __restrict__ wdw,
             const short* __restrict__ bph, const short* __restrict__ bpl,
             float* __restrict__ out, int shift, int use_mask, int roll)
{
    __shared__ __align__(16) char smem[50432];
    short* XTh = (short*)smem;                       // A: XTin -> qT -> attn-out
    short* XTl = (short*)(smem + 8320);
    float* scr = (float*)(smem + 16640);             // B: fp32 planes (stride 68)
    short* vbh = (short*)(smem + 16640);             // B: vb after DWv
    short* vbl = (short*)(smem + 24832);
    float* projo = (float*)(smem + 16640);           // B: after P6
    short* kTh = (short*)(smem + 34048);             // C: kT -> PT
    short* kTl = (short*)(smem + 42240);
    short* PTh = kTh;
    short* PTl = kTl;

    const int tid = threadIdx.x, lane = tid & 63, wv = tid >> 6;
    const int col = lane & 15, quad = lane >> 4, qo8 = quad * 8;
    const int mh = wv & 1, nh = wv >> 1;
    const int cp = tid >> 3, rrow = tid & 7;
    const int n = blockIdx.x;
    const int b = n >> 10, c = (n >> 4) & 63, t = n & 15;
    const size_t base = ((size_t)(b * 64 + c)) << 16;

    // ---- P1: load window (shift folded), split via cvt_pk pairs, XTin[p][c2] ----
    #pragma unroll
    for (int k = 0; k < 16; k += 2) {
        int o0 = tid + k * 256, o1 = o0 + 256;
        int hi0 = o0 >> 11, r0 = (o0 >> 8) & 7, lo0 = (o0 >> 3) & 31, s0 = o0 & 7;
        int hi1 = o1 >> 11, r1 = (o1 >> 8) & 7, lo1 = (o1 >> 3) & 31, s1 = o1 & 7;
        float v0 = in[base + (size_t)(((t * 16 + hi0 * 8 + r0) + shift) & 255) * 256
                           + (((lo0 * 8 + s0) + shift) & 255)];
        float v1 = in[base + (size_t)(((t * 16 + hi1 * 8 + r1) + shift) & 255) * 256
                           + (((lo1 * 8 + s1) + shift) & 255)];
        unsigned hw, lw; bsplit2(v0, v1, hw, lw);
        int ad0 = xswz(r0 * 8 + s0, hi0 * 32 + lo0);
        int ad1 = xswz(r1 * 8 + s1, hi1 * 32 + lo1);
        XTh[ad0] = (short)hw; XTh[ad1] = (short)(hw >> 16);
        XTl[ad0] = (short)lw; XTl[ad1] = (short)(lw >> 16);
    }
    __syncthreads();   // (1)

    // ---- P2q -> scr ----
    p2_chunk(XTh, XTl, bqh, bql, scr, 0, mh, nh, col, quad, qo8, lane);
    __syncthreads();   // (2)

    // ---- DWq: dw3x3 q -> dq regs + per-channel norms ----
    float dq[2][8], nq[2];
    dw_pair(scr, wdw, 2 * cp, rrow, dq);
    #pragma unroll
    for (int chi = 0; chi < 2; ++chi) {
        float ss = 0.f;
        #pragma unroll
        for (int s = 0; s < 8; ++s) ss = fmaf(dq[chi][s], dq[chi][s], ss);
        ss += __shfl_xor(ss, 1); ss += __shfl_xor(ss, 2); ss += __shfl_xor(ss, 4);
        nq[chi] = fmaxf(sqrtf(ss), 1e-12f);
    }
    __syncthreads();   // (3) scr reads done

    // ---- P2k -> scr ----
    p2_chunk(XTh, XTl, bqh, bql, scr, 1, mh, nh, col, quad, qo8, lane);
    __syncthreads();   // (4)

    // ---- DWk: dw3x3 k -> regs, fold 0.125/(nq*nk), scatter -> kT ----
    {
        float dk[2][8];
        dw_pair(scr, wdw + 64 * 9, 2 * cp, rrow, dk);
        #pragma unroll
        for (int chi = 0; chi < 2; ++chi) {
            float ss = 0.f;
            #pragma unroll
            for (int s = 0; s < 8; ++s) ss = fmaf(dk[chi][s], dk[chi][s], ss);
            ss += __shfl_xor(ss, 1); ss += __shfl_xor(ss, 2); ss += __shfl_xor(ss, 4);
            float nk = fmaxf(sqrtf(ss), 1e-12f);
            float sc = 0.125f / (nq[chi] * nk);
            #pragma unroll
            for (int s = 0; s < 8; ++s) dk[chi][s] *= sc;
        }
        #pragma unroll
        for (int s0 = 0; s0 < 8; ++s0) {       // reg->LDS transposed scatter, 2-way free
            unsigned hw, lw; bsplit2(dk[0][s0], dk[1][s0], hw, lw);
            int ad = xswz(rrow * 8 + s0, 2 * cp);
            *(unsigned*)&kTh[ad] = hw; *(unsigned*)&kTl[ad] = lw;
        }
    }
    __syncthreads();   // (5) scr reads done

    // ---- P2v -> scr (last XTin reader) ----
    p2_chunk(XTh, XTl, bqh, bql, scr, 2, mh, nh, col, quad, qo8, lane);
    __syncthreads();   // (6)

    // ---- DWv -> dv regs ; scatter dq -> qT (A free now) ; zero A row 64 ----
    float dv[2][8];
    dw_pair(scr, wdw + 128 * 9, 2 * cp, rrow, dv);
    #pragma unroll
    for (int s0 = 0; s0 < 8; ++s0) {
        unsigned hw, lw; bsplit2(dq[0][s0], dq[1][s0], hw, lw);
        int ad = xswz(rrow * 8 + s0, 2 * cp);
        *(unsigned*)&XTh[ad] = hw; *(unsigned*)&XTl[ad] = lw;
    }
    if (tid < 32) {
        *(unsigned*)&XTh[4096 + 2 * tid] = 0u;
        *(unsigned*)&XTl[4096 + 2 * tid] = 0u;
    }
    __syncthreads();   // (7) scr reads done, qT/kT ready

    // ---- VB: dv regs -> vb[c][i] (B region) ----
    #pragma unroll
    for (int chi = 0; chi < 2; ++chi) {
        unsigned hw[4], lw[4];
        #pragma unroll
        for (int q2 = 0; q2 < 4; ++q2) bsplit2(dv[chi][2 * q2], dv[chi][2 * q2 + 1], hw[q2], lw[q2]);
        int ch = 2 * cp + chi;
        int ad = ch * 64 + ((rrow ^ xkey(ch)) << 3);
        *(uint4*)&vbh[ad] = (uint4){hw[0], hw[1], hw[2], hw[3]};
        *(uint4*)&vbl[ad] = (uint4){lw[0], lw[1], lw[2], lw[3]};
    }

    // ---- P5: MFMA QK^T (M=i rows wv*16.., N=j all 64, K=c) + mask + softmax ----
    f32x4 at[4];
    #pragma unroll
    for (int nt = 0; nt < 4; ++nt) at[nt] = (f32x4){0.f, 0.f, 0.f, 0.f};
    {
        bf8 Ah[2], Al[2];
        #pragma unroll
        for (int kk = 0; kk < 2; ++kk) {
            int row = wv * 16 + col;
            int ad = row * 64 + ((kk * 32 + qo8) ^ (xkey(row) << 3));
            Ah[kk] = *(const bf8*)&XTh[ad];   // qT
            Al[kk] = *(const bf8*)&XTl[ad];
        }
        #pragma unroll
        for (int kk = 0; kk < 2; ++kk)
            #pragma unroll
            for (int nt = 0; nt < 4; ++nt) {
                int rowB = nt * 16 + col;
                int ad = rowB * 64 + ((kk * 32 + qo8) ^ (xkey(rowB) << 3));
                bf8 Bh = *(const bf8*)&kTh[ad];
                bf8 Bl = *(const bf8*)&kTl[ad];
                at[nt] = MFMA(Ah[kk], Bh, at[nt]);
                at[nt] = MFMA(Ah[kk], Bl, at[nt]);
                at[nt] = MFMA(Al[kk], Bh, at[nt]);
            }
    }
    if (use_mask) {
        const int widx = n & 1023;
        const int hn_m = widx >> 5, wn_m = widx & 31;
        #pragma unroll
        for (int nt = 0; nt < 4; ++nt) {
            int j = nt * 16 + col;
            int rj = ((hn_m == 31) ? (((j >> 3) < 4) ? 1 : 2) : 0) * 3
                   + ((wn_m == 31) ? (((j & 7) < 4) ? 1 : 2) : 0);
            #pragma unroll
            for (int rg = 0; rg < 4; ++rg) {
                int i = wv * 16 + quad * 4 + rg;
                int ri = ((hn_m == 31) ? (((i >> 3) < 4) ? 1 : 2) : 0) * 3
                       + ((wn_m == 31) ? (((i & 7) < 4) ? 1 : 2) : 0);
                if (ri != rj) at[nt][rg] = at[nt][rg] - 100.f;
            }
        }
    }
    float Pv[4][4];
    #pragma unroll
    for (int rg = 0; rg < 4; ++rg) {
        float m = fmaxf(fmaxf(at[0][rg], at[1][rg]), fmaxf(at[2][rg], at[3][rg]));
        m = fmaxf(m, __shfl_xor(m, 1)); m = fmaxf(m, __shfl_xor(m, 2));
        m = fmaxf(m, __shfl_xor(m, 4)); m = fmaxf(m, __shfl_xor(m, 8));
        float e0 = __expf(at[0][rg] - m), e1 = __expf(at[1][rg] - m);
        float e2 = __expf(at[2][rg] - m), e3 = __expf(at[3][rg] - m);
        float s = e0 + e1 + e2 + e3;
        s += __shfl_xor(s, 1); s += __shfl_xor(s, 2);
        s += __shfl_xor(s, 4); s += __shfl_xor(s, 8);
        float is = 1.0f / s;
        Pv[0][rg] = e0 * is; Pv[1][rg] = e1 * is; Pv[2][rg] = e2 * is; Pv[3][rg] = e3 * is;
    }
    __syncthreads();   // (8) qT/kT reads done

    // ---- PT write: PT[j][i] (overlays kT) ----
    #pragma unroll
    for (int nt = 0; nt < 4; ++nt) {
        int j = nt * 16 + col;
        #pragma unroll
        for (int rp = 0; rp < 2; ++rp) {
            unsigned hw, lw; bsplit2(Pv[nt][2 * rp], Pv[nt][2 * rp + 1], hw, lw);
            int i0 = wv * 16 + quad * 4 + 2 * rp;
            int ad = j * 64 + (i0 ^ (xkey(j) << 3));
            *(unsigned*)&PTh[ad] = hw; *(unsigned*)&PTl[ad] = lw;
        }
    }
    __syncthreads();   // (9)

    // ---- P6: MFMA V*A. M=c, N=j, K=i. A=vb[c][i], B=PT[j][i]. D -> XT[p=j][c] ----
    {
        f32x4 av[2][2];
        #pragma unroll
        for (int mt = 0; mt < 2; ++mt)
            #pragma unroll
            for (int nt = 0; nt < 2; ++nt) av[mt][nt] = (f32x4){0.f, 0.f, 0.f, 0.f};
        #pragma unroll
        for (int kk = 0; kk < 2; ++kk) {
            bf8 Ah[2], Al[2], Bh[2], Bl[2];
            #pragma unroll
            for (int mt = 0; mt < 2; ++mt) {
                int row = (mh * 2 + mt) * 16 + col;
                int ad = row * 64 + ((kk * 32 + qo8) ^ (xkey(row) << 3));
                Ah[mt] = *(const bf8*)&vbh[ad];
                Al[mt] = *(const bf8*)&vbl[ad];
            }
            #pragma unroll
            for (int nt = 0; nt < 2; ++nt) {
                int rowB = (nh * 2 + nt) * 16 + col;
                int ad = rowB * 64 + ((kk * 32 + qo8) ^ (xkey(rowB) << 3));
                Bh[nt] = *(const bf8*)&PTh[ad];
                Bl[nt] = *(const bf8*)&PTl[ad];
            }
            #pragma unroll
            for (int mt = 0; mt < 2; ++mt)
                #pragma unroll
                for (int nt = 0; nt < 2; ++nt) {
                    av[mt][nt] = MFMA(Ah[mt], Bh[nt], av[mt][nt]);
                    av[mt][nt] = MFMA(Ah[mt], Bl[nt], av[mt][nt]);
                    av[mt][nt] = MFMA(Al[mt], Bh[nt], av[mt][nt]);
                }
        }
        #pragma unroll
        for (int nt = 0; nt < 2; ++nt) {
            int j = (nh * 2 + nt) * 16 + col;
            #pragma unroll
            for (int mt = 0; mt < 2; ++mt) {
                int c0 = (mh * 2 + mt) * 16 + quad * 4;
                #pragma unroll
                for (int rp = 0; rp < 2; ++rp) {
                    unsigned hw, lw; bsplit2(av[mt][nt][2 * rp], av[mt][nt][2 * rp + 1], hw, lw);
                    int ad = j * 64 + ((c0 + 2 * rp) ^ (xkey(j) << 3));
                    *(unsigned*)&XTh[ad] = hw;
                    *(unsigned*)&XTl[ad] = lw;
                }
            }
        }
    }
    __syncthreads();   // (10)

    // ---- P7: MFMA proj conv = 9 shifted GEMMs. M=p, N=oc, K=ic ----
    {
        f32x4 ap[2][2];
        #pragma unroll
        for (int mt = 0; mt < 2; ++mt)
            #pragma unroll
            for (int nt = 0; nt < 2; ++nt) ap[mt][nt] = (f32x4){0.f, 0.f, 0.f, 0.f};
        const int smc = col & 7;
        #pragma unroll 1
        for (int tap = 0; tap < 9; ++tap) {
            int dy = (tap >= 6) ? 1 : ((tap >= 3) ? 0 : -1);
            int dx = tap - (dy + 1) * 3 - 1;
            int ra[2];
            #pragma unroll
            for (int mt = 0; mt < 2; ++mt) {
                int rr = (mh * 2 + mt) * 2 + (col >> 3) + dy;
                int ss = smc + dx;
                bool ok = ((unsigned)rr < 8u) && ((unsigned)ss < 8u);
                ra[mt] = ok ? (rr * 8 + ss) : 64;   // row 64 = zeros
            }
            #pragma unroll
            for (int kk = 0; kk < 2; ++kk) {
                bf8 Bh[2], Bl[2], Ah[2], Al[2];
                #pragma unroll
                for (int nt = 0; nt < 2; ++nt) {
                    int bi = (((tap * 2 + kk) * 4 + (nh * 2 + nt)) * 64 + lane) * 8;
                    Bh[nt] = *(const bf8*)&bph[bi];
                    Bl[nt] = *(const bf8*)&bpl[bi];
                }
                #pragma unroll
                for (int mt = 0; mt < 2; ++mt) {
                    int ad = ra[mt] * 64 + ((kk * 32 + qo8) ^ (xkey(ra[mt]) << 3));
                    Ah[mt] = *(const bf8*)&XTh[ad];
                    Al[mt] = *(const bf8*)&XTl[ad];
                }
                #pragma unroll
                for (int mt = 0; mt < 2; ++mt)
                    #pragma unroll
                    for (int nt = 0; nt < 2; ++nt) {
                        ap[mt][nt] = MFMA(Ah[mt], Bh[nt], ap[mt][nt]);
                        ap[mt][nt] = MFMA(Ah[mt], Bl[nt], ap[mt][nt]);
                        ap[mt][nt] = MFMA(Al[mt], Bh[nt], ap[mt][nt]);
                    }
            }
        }
        #pragma unroll
        for (int nt = 0; nt < 2; ++nt) {
            int oc = (nh * 2 + nt) * 16 + col;
            #pragma unroll
            for (int mt = 0; mt < 2; ++mt) {
                int p0 = (mh * 2 + mt) * 16 + quad * 4;
                *(f32x4*)&projo[pswz68(oc, p0)] = ap[mt][nt];
            }
        }
    }
    __syncthreads();   // (11)

    // ---- P8: window reverse + roll, coalesced image-order stores ----
    #pragma unroll
    for (int k = 0; k < 16; ++k) {
        int o = tid + k * 256;
        int hi = o >> 11, r = (o >> 8) & 7, lo = (o >> 3) & 31, s = o & 7;
        int c2 = hi * 32 + lo;
        float v = projo[pswz68(c2, r * 8 + s)];
        int h2 = t * 16 + hi * 8 + r, w2 = lo * 8 + s;
        out[base + (size_t)((h2 + roll) & 255) * 256 + ((w2 + roll) & 255)] = v;
    }
}

extern "C" void kernel_launch(void* const* d_in, const int* in_sizes, int n_in,
                              void* d_out, int out_size, void* d_ws, size_t ws_size,
                              hipStream_t stream)
{
    const float* x      = (const float*)d_in[0];
    const float* wqkv0  = (const float*)d_in[1];
    const float* wdw0   = (const float*)d_in[2];
    const float* wproj0 = (const float*)d_in[3];
    const float* wqkv1  = (const float*)d_in[4];
    const float* wdw1   = (const float*)d_in[5];
    const float* wproj1 = (const float*)d_in[6];
    float* out = (float*)d_out;

    float* tmp = (float*)d_ws;                       // 33,554,432 floats (134 MB)
    short* fb  = (short*)(tmp + 33554432);
    short* bq0h = fb;                                // 12288 each
    short* bq0l = fb + 12288;
    short* bq1h = fb + 24576;
    short* bq1l = fb + 36864;
    short* bp0h = fb + 49152;                        // 36864 each
    short* bp0l = fb + 86016;
    short* bp1h = fb + 122880;
    short* bp1l = fb + 159744;

    hipLaunchKernelGGL(k_fq, dim3(24), dim3(512), 0, stream, wqkv0, bq0h, bq0l);
    hipLaunchKernelGGL(k_fq, dim3(24), dim3(512), 0, stream, wqkv1, bq1h, bq1l);
    hipLaunchKernelGGL(k_fp, dim3(72), dim3(512), 0, stream, wproj0, bp0h, bp0l);
    hipLaunchKernelGGL(k_fp, dim3(72), dim3(512), 0, stream, wproj1, bp1h, bp1l);

    // pass 1: x -> tmp (no shift/mask/roll)
    hipLaunchKernelGGL(k_fused, dim3(8192), dim3(256), 0, stream,
                       x, bq0h, bq0l, wdw0, bp0h, bp0l, tmp, 0, 0, 0);
    // pass 2: tmp -> out (shift +4 read, Swin mask, roll +4 write)
    hipLaunchKernelGGL(k_fused, dim3(8192), dim3(256), 0, stream,
                       tmp, bq1h, bq1l, wdw1, bp1h, bp1l, out, 4, 1, 4);
}

// Round 4
// 624.191 us; speedup vs baseline: 1.3605x; 1.0183x over previous
//
#include <hip/hip_runtime.h>

// LocalAttention (Swin scrambled-window variant) — all four GEMMs on MFMA.
// Window map (verified pass R2/R3): n=b*1024+c*16+t ; c2=hi*32+lo ; p=r*8+s ;
// h=16t+8hi+r ; w=8lo+s ; mask index = n&1023.
// l2norm folds into k:  attn[i][j] = sum_c q[c][i] * (k[c][j]*0.125/(nq_c*nk_c)).
// Split-bf16 everywhere: x=hi+lo, D += Ah*Bh + Ah*Bl + Al*Bh (rel err ~2^-18).
//
// R7: 4 blocks/CU via LDS 50.4KB -> 40960B exactly (163840/4; alloc granule 512).
//   - scr = ONE 32-channel fp32 chunk (8KB); front = 6 serial P2->DW chunk pairs,
//     DW remapped to 1 channel/thread (ch=tid>>3, rrow=tid&7).
//   - No pad row: P7 OOB A-reads redirect to a 128B zero span at byte 32768 via
//     magic rows ra_h=256 (XTh base) / ra_l=192 (XTl base) — same span, xkey=0.
//     Span zeroed in a tiny phase after P6 (PT dead then).
//   - vb deferred post-P5 (dv in regs) overlaying dead kT; PT in two 32-row
//     pieces overlaying dead scr; P6 split into j-halves (all 4 waves active);
//     projo stride-64 granule-8 XOR overlaying dead vb.
//   Arena: R1[0,16384) XTin->qT->XTout ; R2[16384,32768) kT->vb->projo(+R3) ;
//          R3[32768,40960) scr->PT pieces (+zero span at P7).
//   20 barriers; __launch_bounds__(256,4).

typedef __attribute__((ext_vector_type(8))) short bf8;
typedef __attribute__((ext_vector_type(4))) float f32x4;
#define MFMA(a, b, c) __builtin_amdgcn_mfma_f32_16x16x32_bf16(a, b, c, 0, 0, 0)

__device__ __forceinline__ int xkey(int p) { return ((p >> 3) ^ p) & 7; }
// bf16 regions: row p, col c -> short index (stride 64, granule-8 XOR)
__device__ __forceinline__ int xswz(int p, int c) { return p * 64 + (c ^ (xkey(p) << 3)); }
// scr fp32 (32 ch): stride 64, granule-4 XOR (uniform for P2 store + dw stencil)
__device__ __forceinline__ int sswz(int ch, int p) {
    return ch * 64 + (p ^ (((ch >> 1) & 7) << 2));
}
// projo fp32 (64 ch): stride 64, granule-8 XOR (uniform store, 2-way P8 read)
__device__ __forceinline__ int jswz(int ch, int p) {
    return ch * 64 + (p ^ (((ch >> 1) & 7) << 3));
}

// packed 2xf32 -> 2xbf16 (RNE). No builtin on gfx950 — inline asm (T12/m240).
__device__ __forceinline__ unsigned cvtpk(float a, float b) {
    unsigned r;
    asm("v_cvt_pk_bf16_f32 %0, %1, %2" : "=v"(r) : "v"(a), "v"(b));
    return r;
}

__device__ __forceinline__ void bsplit(float f, short& h, short& l) {
    unsigned u = __float_as_uint(f);
    unsigned hb = (u + 0x7FFFu + ((u >> 16) & 1u)) >> 16;
    float hf = __uint_as_float(hb << 16);
    float r = f - hf;
    unsigned u2 = __float_as_uint(r);
    unsigned lb = (u2 + 0x7FFFu + ((u2 >> 16) & 1u)) >> 16;
    h = (short)hb; l = (short)lb;
}
// a in low half, b in high half. hi = RNE-bf16(x); lo = RNE-bf16(x - hi).
__device__ __forceinline__ void bsplit2(float a, float b, unsigned& hw, unsigned& lw) {
    hw = cvtpk(a, b);
    float ra = a - __uint_as_float(hw << 16);
    float rb = b - __uint_as_float(hw & 0xFFFF0000u);
    lw = cvtpk(ra, rb);
}

// ---- qkv 1x1 weight fragments: [kk(2)][tt(12)][lane(64)][j(8)]  B[n=oc][k=ic] ----
__global__ void k_fq(const float* __restrict__ wq, short* __restrict__ oh, short* __restrict__ ol) {
    int bx = blockIdx.x;                 // kk*12 + tt
    int kk = bx / 12, tt = bx % 12;
    int tid = threadIdx.x;               // 512
    int lane = tid >> 3, j = tid & 7;
    int oc = tt * 16 + (lane & 15);
    int ic = kk * 32 + ((lane >> 4) << 3) + j;
    short h, l; bsplit(wq[oc * 64 + ic], h, l);
    oh[bx * 512 + tid] = h; ol[bx * 512 + tid] = l;
}
// ---- proj 3x3 weight fragments: [tap(9)][kk(2)][tt(4)][lane(64)][j(8)] ----
__global__ void k_fp(const float* __restrict__ wp, short* __restrict__ oh, short* __restrict__ ol) {
    int bx = blockIdx.x;                 // tap*8 + kk*4 + tt
    int tap = bx >> 3, kk = (bx >> 2) & 1, tt = bx & 3;
    int tid = threadIdx.x;
    int lane = tid >> 3, j = tid & 7;
    int oc = tt * 16 + (lane & 15);
    int ic = kk * 32 + ((lane >> 4) << 3) + j;
    short h, l; bsplit(wp[(oc * 64 + ic) * 9 + tap], h, l);
    oh[bx * 512 + tid] = h; ol[bx * 512 + tid] = l;
}

// dw3x3 for ONE channel (local ch 0..31 in scr), one output row, zero pad.
__device__ __forceinline__ void dw_one(const float* scr, const float* wd,
                                       int ch, int row, float o[8]) {
    float w9[9];
    #pragma unroll
    for (int tp = 0; tp < 9; ++tp) w9[tp] = wd[tp];
    float e[3][10];
    #pragma unroll
    for (int k3 = 0; k3 < 3; ++k3) {
        int rr = row - 1 + k3;
        e[k3][0] = 0.f; e[k3][9] = 0.f;
        if ((unsigned)rr < 8u) {
            float4 a = *(const float4*)&scr[sswz(ch, rr * 8)];
            float4 b = *(const float4*)&scr[sswz(ch, rr * 8 + 4)];
            e[k3][1] = a.x; e[k3][2] = a.y; e[k3][3] = a.z; e[k3][4] = a.w;
            e[k3][5] = b.x; e[k3][6] = b.y; e[k3][7] = b.z; e[k3][8] = b.w;
        } else {
            #pragma unroll
            for (int q2 = 1; q2 < 9; ++q2) e[k3][q2] = 0.f;
        }
    }
    #pragma unroll
    for (int s = 0; s < 8; ++s) {
        float a = 0.f;
        #pragma unroll
        for (int k3 = 0; k3 < 3; ++k3)
            #pragma unroll
            for (int dx = 0; dx < 3; ++dx)
                a = fmaf(w9[k3 * 3 + dx], e[k3][s + dx], a);
        o[s] = a;
    }
}

__device__ __forceinline__ float norm8(const float d[8]) {
    float ss = 0.f;
    #pragma unroll
    for (int s = 0; s < 8; ++s) ss = fmaf(d[s], d[s], ss);
    ss += __shfl_xor(ss, 1); ss += __shfl_xor(ss, 2); ss += __shfl_xor(ss, 4);
    return fmaxf(sqrtf(ss), 1e-12f);
}

// P2 chunk: 64px x 32oc x 64ic MFMA 1x1, XTin -> scr. chunk 0..5 = q0,q1,k0,k1,v0,v1.
__device__ __forceinline__ void p2_chunk32(const short* XTh, const short* XTl,
                                           const short* bqh, const short* bql,
                                           float* scr, int chunk,
                                           int mh, int nh, int col, int quad, int qo8, int lane)
{
    f32x4 acc[2];
    #pragma unroll
    for (int mt = 0; mt < 2; ++mt) acc[mt] = (f32x4){0.f, 0.f, 0.f, 0.f};
    #pragma unroll
    for (int kk = 0; kk < 2; ++kk) {
        bf8 Ah[2], Al[2];
        #pragma unroll
        for (int mt = 0; mt < 2; ++mt) {
            int row = (mh * 2 + mt) * 16 + col;
            int ad = row * 64 + ((kk * 32 + qo8) ^ (xkey(row) << 3));
            Ah[mt] = *(const bf8*)&XTh[ad];
            Al[mt] = *(const bf8*)&XTl[ad];
        }
        int tt = chunk * 2 + nh;
        bf8 Bh = *(const bf8*)&bqh[((kk * 12 + tt) * 64 + lane) * 8];
        bf8 Bl = *(const bf8*)&bql[((kk * 12 + tt) * 64 + lane) * 8];
        #pragma unroll
        for (int mt = 0; mt < 2; ++mt) {
            acc[mt] = MFMA(Ah[mt], Bh, acc[mt]);
            acc[mt] = MFMA(Ah[mt], Bl, acc[mt]);
            acc[mt] = MFMA(Al[mt], Bh, acc[mt]);
        }
    }
    #pragma unroll
    for (int mt = 0; mt < 2; ++mt) {
        int ocl = nh * 16 + col;
        int p0 = (mh * 2 + mt) * 16 + quad * 4;
        *(f32x4*)&scr[sswz(ocl, p0)] = acc[mt];
    }
}

__global__ __launch_bounds__(256, 4)
void k_fused(const float* __restrict__ in,
             const short* __restrict__ bqh, const short* __restrict__ bql,
             const float* __restrict__ wdw,
             const short* __restrict__ bph, const short* __restrict__ bpl,
             float* __restrict__ out, int shift, int use_mask, int roll)
{
    __shared__ __align__(16) char smem[40960];
    short* XTh = (short*)smem;                 // R1: XTin -> qT -> XTout
    short* XTl = (short*)(smem + 8192);
    short* kTh = (short*)(smem + 16384);       // R2: kT -> vb ; projo overlays later
    short* kTl = (short*)(smem + 24576);
    short* vbh = kTh;
    short* vbl = kTl;
    float* scr = (float*)(smem + 32768);       // R3: scr -> PT pieces -> zero span
    short* PTh = (short*)(smem + 32768);       // 32 rows x 64 shorts
    short* PTl = (short*)(smem + 36864);
    float* projo = (float*)(smem + 16384);     // after P6: [16384,32768)

    const int tid = threadIdx.x, lane = tid & 63, wv = tid >> 6;
    const int col = lane & 15, quad = lane >> 4, qo8 = quad * 8;
    const int mh = wv & 1, nh = wv >> 1;
    const int ch = tid >> 3, rrow = tid & 7;   // DW map: 1 channel/thread
    const int n = blockIdx.x;
    const int b = n >> 10, c = (n >> 4) & 63, t = n & 15;
    const size_t base = ((size_t)(b * 64 + c)) << 16;

    // ---- P1: load window (shift folded), split via cvt_pk pairs, XTin[p][c2] ----
    #pragma unroll
    for (int k = 0; k < 16; k += 2) {
        int o0 = tid + k * 256, o1 = o0 + 256;
        int hi0 = o0 >> 11, r0 = (o0 >> 8) & 7, lo0 = (o0 >> 3) & 31, s0 = o0 & 7;
        int hi1 = o1 >> 11, r1 = (o1 >> 8) & 7, lo1 = (o1 >> 3) & 31, s1 = o1 & 7;
        float v0 = in[base + (size_t)(((t * 16 + hi0 * 8 + r0) + shift) & 255) * 256
                           + (((lo0 * 8 + s0) + shift) & 255)];
        float v1 = in[base + (size_t)(((t * 16 + hi1 * 8 + r1) + shift) & 255) * 256
                           + (((lo1 * 8 + s1) + shift) & 255)];
        unsigned hw, lw; bsplit2(v0, v1, hw, lw);
        int ad0 = xswz(r0 * 8 + s0, hi0 * 32 + lo0);
        int ad1 = xswz(r1 * 8 + s1, hi1 * 32 + lo1);
        XTh[ad0] = (short)hw; XTh[ad1] = (short)(hw >> 16);
        XTl[ad0] = (short)lw; XTl[ad1] = (short)(lw >> 16);
    }
    __syncthreads();   // (1)

    float dqA[8], dqB[8], dvA[8], dvB[8];
    float nqA, nqB;

    // ---- q0 ----
    p2_chunk32(XTh, XTl, bqh, bql, scr, 0, mh, nh, col, quad, qo8, lane);
    __syncthreads();   // (2)
    dw_one(scr, wdw + ch * 9, ch, rrow, dqA);
    nqA = norm8(dqA);
    __syncthreads();   // (3)
    // ---- q1 ----
    p2_chunk32(XTh, XTl, bqh, bql, scr, 1, mh, nh, col, quad, qo8, lane);
    __syncthreads();   // (4)
    dw_one(scr, wdw + (32 + ch) * 9, ch, rrow, dqB);
    nqB = norm8(dqB);
    __syncthreads();   // (5)
    // ---- k0 ----
    p2_chunk32(XTh, XTl, bqh, bql, scr, 2, mh, nh, col, quad, qo8, lane);
    __syncthreads();   // (6)
    {
        float dk[8];
        dw_one(scr, wdw + (64 + ch) * 9, ch, rrow, dk);
        float sc = 0.125f / (nqA * norm8(dk));
        #pragma unroll
        for (int s = 0; s < 8; ++s) dk[s] *= sc;
        #pragma unroll
        for (int s0 = 0; s0 < 8; s0 += 2) {
            unsigned hw, lw; bsplit2(dk[s0], dk[s0 + 1], hw, lw);
            int p0 = rrow * 8 + s0;
            int a0 = xswz(p0, ch), a1 = xswz(p0 + 1, ch);
            kTh[a0] = (short)hw; kTh[a1] = (short)(hw >> 16);
            kTl[a0] = (short)lw; kTl[a1] = (short)(lw >> 16);
        }
    }
    __syncthreads();   // (7)
    // ---- k1 ----
    p2_chunk32(XTh, XTl, bqh, bql, scr, 3, mh, nh, col, quad, qo8, lane);
    __syncthreads();   // (8)
    {
        float dk[8];
        dw_one(scr, wdw + (96 + ch) * 9, ch, rrow, dk);
        float sc = 0.125f / (nqB * norm8(dk));
        #pragma unroll
        for (int s = 0; s < 8; ++s) dk[s] *= sc;
        int cg = 32 + ch;
        #pragma unroll
        for (int s0 = 0; s0 < 8; s0 += 2) {
            unsigned hw, lw; bsplit2(dk[s0], dk[s0 + 1], hw, lw);
            int p0 = rrow * 8 + s0;
            int a0 = xswz(p0, cg), a1 = xswz(p0 + 1, cg);
            kTh[a0] = (short)hw; kTh[a1] = (short)(hw >> 16);
            kTl[a0] = (short)lw; kTl[a1] = (short)(lw >> 16);
        }
    }
    __syncthreads();   // (9)
    // ---- v0 ----
    p2_chunk32(XTh, XTl, bqh, bql, scr, 4, mh, nh, col, quad, qo8, lane);
    __syncthreads();   // (10)
    dw_one(scr, wdw + (128 + ch) * 9, ch, rrow, dvA);
    __syncthreads();   // (11)
    // ---- v1 (last XTin reader) ----
    p2_chunk32(XTh, XTl, bqh, bql, scr, 5, mh, nh, col, quad, qo8, lane);
    __syncthreads();   // (12)
    // ---- DWv1 + scatter dq -> qT (R1 free now) ----
    dw_one(scr, wdw + (160 + ch) * 9, ch, rrow, dvB);
    #pragma unroll
    for (int s0 = 0; s0 < 8; s0 += 2) {
        unsigned hw, lw; bsplit2(dqA[s0], dqA[s0 + 1], hw, lw);
        int p0 = rrow * 8 + s0;
        int a0 = xswz(p0, ch), a1 = xswz(p0 + 1, ch);
        XTh[a0] = (short)hw; XTh[a1] = (short)(hw >> 16);
        XTl[a0] = (short)lw; XTl[a1] = (short)(lw >> 16);
    }
    {
        int cg = 32 + ch;
        #pragma unroll
        for (int s0 = 0; s0 < 8; s0 += 2) {
            unsigned hw, lw; bsplit2(dqB[s0], dqB[s0 + 1], hw, lw);
            int p0 = rrow * 8 + s0;
            int a0 = xswz(p0, cg), a1 = xswz(p0 + 1, cg);
            XTh[a0] = (short)hw; XTh[a1] = (short)(hw >> 16);
            XTl[a0] = (short)lw; XTl[a1] = (short)(lw >> 16);
        }
    }
    __syncthreads();   // (13) qT/kT ready

    // ---- P5: MFMA QK^T (M=i rows wv*16.., N=j all 64, K=c) + mask + softmax ----
    f32x4 at[4];
    #pragma unroll
    for (int nt = 0; nt < 4; ++nt) at[nt] = (f32x4){0.f, 0.f, 0.f, 0.f};
    {
        bf8 Ah[2], Al[2];
        #pragma unroll
        for (int kk = 0; kk < 2; ++kk) {
            int row = wv * 16 + col;
            int ad = row * 64 + ((kk * 32 + qo8) ^ (xkey(row) << 3));
            Ah[kk] = *(const bf8*)&XTh[ad];   // qT
            Al[kk] = *(const bf8*)&XTl[ad];
        }
        #pragma unroll
        for (int kk = 0; kk < 2; ++kk)
            #pragma unroll
            for (int nt = 0; nt < 4; ++nt) {
                int rowB = nt * 16 + col;
                int ad = rowB * 64 + ((kk * 32 + qo8) ^ (xkey(rowB) << 3));
                bf8 Bh = *(const bf8*)&kTh[ad];
                bf8 Bl = *(const bf8*)&kTl[ad];
                at[nt] = MFMA(Ah[kk], Bh, at[nt]);
                at[nt] = MFMA(Ah[kk], Bl, at[nt]);
                at[nt] = MFMA(Al[kk], Bh, at[nt]);
            }
    }
    if (use_mask) {
        const int widx = n & 1023;
        const int hn_m = widx >> 5, wn_m = widx & 31;
        #pragma unroll
        for (int nt = 0; nt < 4; ++nt) {
            int j = nt * 16 + col;
            int rj = ((hn_m == 31) ? (((j >> 3) < 4) ? 1 : 2) : 0) * 3
                   + ((wn_m == 31) ? (((j & 7) < 4) ? 1 : 2) : 0);
            #pragma unroll
            for (int rg = 0; rg < 4; ++rg) {
                int i = wv * 16 + quad * 4 + rg;
                int ri = ((hn_m == 31) ? (((i >> 3) < 4) ? 1 : 2) : 0) * 3
                       + ((wn_m == 31) ? (((i & 7) < 4) ? 1 : 2) : 0);
                if (ri != rj) at[nt][rg] = at[nt][rg] - 100.f;
            }
        }
    }
    float Pv[4][4];
    #pragma unroll
    for (int rg = 0; rg < 4; ++rg) {
        float m = fmaxf(fmaxf(at[0][rg], at[1][rg]), fmaxf(at[2][rg], at[3][rg]));
        m = fmaxf(m, __shfl_xor(m, 1)); m = fmaxf(m, __shfl_xor(m, 2));
        m = fmaxf(m, __shfl_xor(m, 4)); m = fmaxf(m, __shfl_xor(m, 8));
        float e0 = __expf(at[0][rg] - m), e1 = __expf(at[1][rg] - m);
        float e2 = __expf(at[2][rg] - m), e3 = __expf(at[3][rg] - m);
        float s = e0 + e1 + e2 + e3;
        s += __shfl_xor(s, 1); s += __shfl_xor(s, 2);
        s += __shfl_xor(s, 4); s += __shfl_xor(s, 8);
        float is = 1.0f / s;
        Pv[0][rg] = e0 * is; Pv[1][rg] = e1 * is; Pv[2][rg] = e2 * is; Pv[3][rg] = e3 * is;
    }
    __syncthreads();   // (14) qT/kT reads done

    // ---- VB (dv regs -> vb, overlays dead kT) + PT piece 0 (j 0..31) ----
    #pragma unroll
    for (int hf = 0; hf < 2; ++hf) {
        const float* dv = hf ? dvB : dvA;
        int cg = hf * 32 + ch;
        unsigned hw[4], lw[4];
        #pragma unroll
        for (int q2 = 0; q2 < 4; ++q2) bsplit2(dv[2 * q2], dv[2 * q2 + 1], hw[q2], lw[q2]);
        int ad = cg * 64 + ((rrow ^ xkey(cg)) << 3);
        *(uint4*)&vbh[ad] = (uint4){hw[0], hw[1], hw[2], hw[3]};
        *(uint4*)&vbl[ad] = (uint4){lw[0], lw[1], lw[2], lw[3]};
    }
    #pragma unroll
    for (int q = 0; q < 2; ++q) {
        int nt = q;                         // piece 0: j-tiles 0,1
        int jl = q * 16 + col;
        #pragma unroll
        for (int rp = 0; rp < 2; ++rp) {
            unsigned hw, lw; bsplit2(Pv[nt][2 * rp], Pv[nt][2 * rp + 1], hw, lw);
            int i0 = wv * 16 + quad * 4 + 2 * rp;
            int ad = jl * 64 + (i0 ^ (xkey(jl) << 3));
            *(unsigned*)&PTh[ad] = hw; *(unsigned*)&PTl[ad] = lw;
        }
    }
    __syncthreads();   // (15)

    // ---- P6 halves: M=c, N=j(32), K=i. A=vb[c][i], B=PT[jl][i]. D -> XT[j][c] ----
    #pragma unroll
    for (int h = 0; h < 2; ++h) {
        if (h == 1) {
            // PT piece 1 (j 32..63) — after half-0's reads
            #pragma unroll
            for (int q = 0; q < 2; ++q) {
                int nt = 2 + q;
                int jl = q * 16 + col;
                #pragma unroll
                for (int rp = 0; rp < 2; ++rp) {
                    unsigned hw, lw; bsplit2(Pv[nt][2 * rp], Pv[nt][2 * rp + 1], hw, lw);
                    int i0 = wv * 16 + quad * 4 + 2 * rp;
                    int ad = jl * 64 + (i0 ^ (xkey(jl) << 3));
                    *(unsigned*)&PTh[ad] = hw; *(unsigned*)&PTl[ad] = lw;
                }
            }
            __syncthreads();   // (17)
        }
        f32x4 av[2];
        #pragma unroll
        for (int mt = 0; mt < 2; ++mt) av[mt] = (f32x4){0.f, 0.f, 0.f, 0.f};
        #pragma unroll
        for (int kk = 0; kk < 2; ++kk) {
            bf8 Ah[2], Al[2];
            #pragma unroll
            for (int mt = 0; mt < 2; ++mt) {
                int row = (mh * 2 + mt) * 16 + col;
                int ad = row * 64 + ((kk * 32 + qo8) ^ (xkey(row) << 3));
                Ah[mt] = *(const bf8*)&vbh[ad];
                Al[mt] = *(const bf8*)&vbl[ad];
            }
            int jl = nh * 16 + col;
            int bd = jl * 64 + ((kk * 32 + qo8) ^ (xkey(jl) << 3));
            bf8 Bh = *(const bf8*)&PTh[bd];
            bf8 Bl = *(const bf8*)&PTl[bd];
            #pragma unroll
            for (int mt = 0; mt < 2; ++mt) {
                av[mt] = MFMA(Ah[mt], Bh, av[mt]);
                av[mt] = MFMA(Ah[mt], Bl, av[mt]);
                av[mt] = MFMA(Al[mt], Bh, av[mt]);
            }
        }
        int j = (h * 2 + nh) * 16 + col;
        #pragma unroll
        for (int mt = 0; mt < 2; ++mt) {
            int c0 = (mh * 2 + mt) * 16 + quad * 4;
            #pragma unroll
            for (int rp = 0; rp < 2; ++rp) {
                unsigned hw, lw; bsplit2(av[mt][2 * rp], av[mt][2 * rp + 1], hw, lw);
                int ad = j * 64 + ((c0 + 2 * rp) ^ (xkey(j) << 3));
                *(unsigned*)&XTh[ad] = hw;
                *(unsigned*)&XTl[ad] = lw;
            }
        }
        __syncthreads();   // (16)/(18)
    }

    // ---- zero span for P7 OOB reads (R3 dead now): bytes [32768,32896) ----
    if (tid < 32) ((unsigned*)(smem + 32768))[tid] = 0u;
    __syncthreads();   // (19)

    // ---- P7: MFMA proj conv = 9 shifted GEMMs. M=p, N=oc, K=ic. OOB -> zero span
    //      via magic rows: ra_h=256 (XTh base) / ra_l=192 (XTl base), xkey=0. ----
    {
        f32x4 ap[2][2];
        #pragma unroll
        for (int mt = 0; mt < 2; ++mt)
            #pragma unroll
            for (int nt = 0; nt < 2; ++nt) ap[mt][nt] = (f32x4){0.f, 0.f, 0.f, 0.f};
        const int smc = col & 7;
        #pragma unroll 1
        for (int tap = 0; tap < 9; ++tap) {
            int dy = (tap >= 6) ? 1 : ((tap >= 3) ? 0 : -1);
            int dx = tap - (dy + 1) * 3 - 1;
            int ra_h[2], ra_l[2];
            #pragma unroll
            for (int mt = 0; mt < 2; ++mt) {
                int rr = (mh * 2 + mt) * 2 + (col >> 3) + dy;
                int ss = smc + dx;
                bool ok = ((unsigned)rr < 8u) && ((unsigned)ss < 8u);
                int row = rr * 8 + ss;
                ra_h[mt] = ok ? row : 256;
                ra_l[mt] = ok ? row : 192;
            }
            #pragma unroll
            for (int kk = 0; kk < 2; ++kk) {
                bf8 Bh[2], Bl[2], Ah[2], Al[2];
                #pragma unroll
                for (int nt = 0; nt < 2; ++nt) {
                    int bi = (((tap * 2 + kk) * 4 + (nh * 2 + nt)) * 64 + lane) * 8;
                    Bh[nt] = *(const bf8*)&bph[bi];
                    Bl[nt] = *(const bf8*)&bpl[bi];
                }
                #pragma unroll
                for (int mt = 0; mt < 2; ++mt) {
                    int adh = ra_h[mt] * 64 + ((kk * 32 + qo8) ^ (xkey(ra_h[mt]) << 3));
                    int adl = ra_l[mt] * 64 + ((kk * 32 + qo8) ^ (xkey(ra_l[mt]) << 3));
                    Ah[mt] = *(const bf8*)&XTh[adh];
                    Al[mt] = *(const bf8*)&XTl[adl];
                }
                #pragma unroll
                for (int mt = 0; mt < 2; ++mt)
                    #pragma unroll
                    for (int nt = 0; nt < 2; ++nt) {
                        ap[mt][nt] = MFMA(Ah[mt], Bh[nt], ap[mt][nt]);
                        ap[mt][nt] = MFMA(Ah[mt], Bl[nt], ap[mt][nt]);
                        ap[mt][nt] = MFMA(Al[mt], Bh[nt], ap[mt][nt]);
                    }
            }
        }
        #pragma unroll
        for (int nt = 0; nt < 2; ++nt) {
            int oc = (nh * 2 + nt) * 16 + col;
            #pragma unroll
            for (int mt = 0; mt < 2; ++mt) {
                int p0 = (mh * 2 + mt) * 16 + quad * 4;
                *(f32x4*)&projo[jswz(oc, p0)] = ap[mt][nt];
            }
        }
    }
    __syncthreads();   // (20)

    // ---- P8: window reverse + roll, coalesced image-order stores ----
    #pragma unroll
    for (int k = 0; k < 16; ++k) {
        int o = tid + k * 256;
        int hi = o >> 11, r = (o >> 8) & 7, lo = (o >> 3) & 31, s = o & 7;
        int c2 = hi * 32 + lo;
        float v = projo[jswz(c2, r * 8 + s)];
        int h2 = t * 16 + hi * 8 + r, w2 = lo * 8 + s;
        out[base + (size_t)((h2 + roll) & 255) * 256 + ((w2 + roll) & 255)] = v;
    }
}

extern "C" void kernel_launch(void* const* d_in, const int* in_sizes, int n_in,
                              void* d_out, int out_size, void* d_ws, size_t ws_size,
                              hipStream_t stream)
{
    const float* x      = (const float*)d_in[0];
    const float* wqkv0  = (const float*)d_in[1];
    const float* wdw0   = (const float*)d_in[2];
    const float* wproj0 = (const float*)d_in[3];
    const float* wqkv1  = (const float*)d_in[4];
    const float* wdw1   = (const float*)d_in[5];
    const float* wproj1 = (const float*)d_in[6];
    float* out = (float*)d_out;

    float* tmp = (float*)d_ws;                       // 33,554,432 floats (134 MB)
    short* fb  = (short*)(tmp + 33554432);
    short* bq0h = fb;                                // 12288 each
    short* bq0l = fb + 12288;
    short* bq1h = fb + 24576;
    short* bq1l = fb + 36864;
    short* bp0h = fb + 49152;                        // 36864 each
    short* bp0l = fb + 86016;
    short* bp1h = fb + 122880;
    short* bp1l = fb + 159744;

    hipLaunchKernelGGL(k_fq, dim3(24), dim3(512), 0, stream, wqkv0, bq0h, bq0l);
    hipLaunchKernelGGL(k_fq, dim3(24), dim3(512), 0, stream, wqkv1, bq1h, bq1l);
    hipLaunchKernelGGL(k_fp, dim3(72), dim3(512), 0, stream, wproj0, bp0h, bp0l);
    hipLaunchKernelGGL(k_fp, dim3(72), dim3(512), 0, stream, wproj1, bp1h, bp1l);

    // pass 1: x -> tmp (no shift/mask/roll)
    hipLaunchKernelGGL(k_fused, dim3(8192), dim3(256), 0, stream,
                       x, bq0h, bq0l, wdw0, bp0h, bp0l, tmp, 0, 0, 0);
    // pass 2: tmp -> out (shift +4 read, Swin mask, roll +4 write)
    hipLaunchKernelGGL(k_fused, dim3(8192), dim3(256), 0, stream,
                       tmp, bq1h, bq1l, wdw1, bp1h, bp1l, out, 4, 1, 4);
}